// Round 8
// baseline (3766.665 us; speedup 1.0000x reference)
//
#include <hip/hip_runtime.h>
#include <hip/hip_fp16.h>
#include <math.h>

#define NN 20000
#define EE 200000
// MUL=128, D=512, EDGE_ATTR=32, HID=32

__device__ __forceinline__ float sspf(float x){
    float sp = (x > 20.f) ? x : log1pf(expf(x));
    return sp - 0.69314718056f;
}

__device__ __forceinline__ void fma8(float* acc, const float* base, float w){
    const float4 a = ((const float4*)base)[0];
    const float4 b = ((const float4*)base)[1];
    acc[0]+=a.x*w; acc[1]+=a.y*w; acc[2]+=a.z*w; acc[3]+=a.w*w;
    acc[4]+=b.x*w; acc[5]+=b.y*w; acc[6]+=b.z*w; acc[7]+=b.w*w;
}

// ---------------- K1: pre irrep_linear -> p1, sdst (p0 consumed in-LDS) ----
__global__ __launch_bounds__(256) void k_pre(
    const float* __restrict__ x, const float* __restrict__ Wp0,
    const float* __restrict__ bp0, const float* __restrict__ Wp1,
    const float* __restrict__ Ws1,
    float* __restrict__ p1, float* __restrict__ sdst)
{
    __shared__ float xl[512][8];    // transposed [feature][node]
    __shared__ float p0l[8][128];
    const int tid = threadIdx.x;
    const int n0 = blockIdx.x * 8;

    for (int it = 0; it < 4; ++it){
        int idx = tid + 256*it;           // 0..1023 float4 slots
        int node = idx >> 7, o4 = idx & 127;
        float4 v = ((const float4*)(x + (size_t)(n0+node)*512))[o4];
        xl[o4*4+0][node]=v.x; xl[o4*4+1][node]=v.y;
        xl[o4*4+2][node]=v.z; xl[o4*4+3][node]=v.w;
    }
    __syncthreads();

    const int j = tid;
    float acc1[8] = {0,0,0,0,0,0,0,0};
    float acc2[8] = {0,0,0,0,0,0,0,0};
    const int o2 = j + 128;               // p1-index in [128,384)
    const int v2 = o2/3, m2 = o2%3;

    if (j < 128){
        for (int u = 0; u < 128; ++u){
            float w1 = Wp0[u*128 + j];
            float w2 = Wp1[u*128 + v2];
            fma8(acc1, &xl[u][0], w1);
            fma8(acc2, &xl[128 + u*3 + m2][0], w2);
        }
        float b = bp0[j];
        #pragma unroll
        for (int n = 0; n < 8; ++n) p0l[n][j] = acc1[n] + b;
    } else {
        const int o1 = j - 128, v1 = o1/3, m1 = o1%3;
        for (int u = 0; u < 128; ++u){
            float w1 = Wp1[u*128 + v1];
            float w2 = Wp1[u*128 + v2];
            fma8(acc1, &xl[128 + u*3 + m1][0], w1);
            fma8(acc2, &xl[128 + u*3 + m2][0], w2);
        }
        #pragma unroll
        for (int n = 0; n < 8; ++n) p1[(size_t)(n0+n)*384 + (j-128)] = acc1[n];
    }
    #pragma unroll
    for (int n = 0; n < 8; ++n) p1[(size_t)(n0+n)*384 + o2] = acc2[n];
    __syncthreads();

    // sdst = p0 @ (Ws1[0:128] + Ws1[128:256])  (the dst-only part of s0@W_s1)
    {
        int n = tid >> 5, h = tid & 31;
        float s = 0.f;
        for (int u = 0; u < 128; ++u){
            float wc = Ws1[u*32 + h] + Ws1[(128+u)*32 + h];
            s += p0l[n][u] * wc;
        }
        sdst[(size_t)(n0+n)*32 + h] = s;
    }
}

// ---------------- K2: gate + node irrep_linear -> self_x -------------------
__global__ __launch_bounds__(256) void k_gate_nd(
    const float* __restrict__ x,
    const float* __restrict__ Wg1, const float* __restrict__ bg1,
    const float* __restrict__ Wg2, const float* __restrict__ bg2,
    const float* __restrict__ Wnd0, const float* __restrict__ bnd0,
    const float* __restrict__ Wnd1,
    float* __restrict__ self_x)
{
    __shared__ float xl[512][8];
    __shared__ float tl[256][8];   // t, then reused for g
    __shared__ float hl[256][8];
    const int tid = threadIdx.x;
    const int n0 = blockIdx.x * 8;

    for (int it = 0; it < 4; ++it){
        int idx = tid + 256*it;
        int node = idx >> 7, o4 = idx & 127;
        float4 v = ((const float4*)(x + (size_t)(n0+node)*512))[o4];
        xl[o4*4+0][node]=v.x; xl[o4*4+1][node]=v.y;
        xl[o4*4+2][node]=v.z; xl[o4*4+3][node]=v.w;
    }
    __syncthreads();

    { // t = [x0, n1]
        int jj = tid;
        if (jj < 128){
            #pragma unroll
            for (int n = 0; n < 8; ++n) tl[jj][n] = xl[jj][n];
        } else {
            int u = jj - 128;
            #pragma unroll
            for (int n = 0; n < 8; ++n){
                float a = xl[128+u*3][n], b = xl[128+u*3+1][n], c = xl[128+u*3+2][n];
                tl[jj][n] = sqrtf((a*a + b*b + c*c) * (1.f/3.f));
            }
        }
    }
    __syncthreads();

    { // h = silu(t @ Wg1 + bg1)
        float acc[8] = {0,0,0,0,0,0,0,0};
        for (int k = 0; k < 256; ++k){
            float w = Wg1[k*256 + tid];
            fma8(acc, &tl[k][0], w);
        }
        float b = bg1[tid];
        #pragma unroll
        for (int n = 0; n < 8; ++n){
            float v = acc[n] + b;
            hl[tid][n] = v / (1.f + expf(-v));
        }
    }
    __syncthreads();

    { // g = h @ Wg2 + bg2  (stored into tl; tl is dead after the barrier)
        float acc[8] = {0,0,0,0,0,0,0,0};
        for (int k = 0; k < 256; ++k){
            float w = Wg2[k*256 + tid];
            fma8(acc, &hl[k][0], w);
        }
        float b = bg2[tid];
        #pragma unroll
        for (int n = 0; n < 8; ++n) tl[tid][n] = acc[n] + b;
    }
    __syncthreads();

    { // xg in-place into xl
        int jj = tid;
        if (jj < 128){
            #pragma unroll
            for (int n = 0; n < 8; ++n) xl[jj][n] = tl[jj][n];
        } else {
            int u = jj - 128;
            #pragma unroll
            for (int n = 0; n < 8; ++n){
                float g1 = tl[128+u][n];
                xl[128+u*3  ][n] *= g1;
                xl[128+u*3+1][n] *= g1;
                xl[128+u*3+2][n] *= g1;
            }
        }
    }
    __syncthreads();

    // nd irrep_linear
    const int j = tid;
    float acc1[8] = {0,0,0,0,0,0,0,0};
    float acc2[8] = {0,0,0,0,0,0,0,0};
    const int o2 = j + 128;
    const int v2 = o2/3, m2 = o2%3;
    if (j < 128){
        for (int u = 0; u < 128; ++u){
            float w1 = Wnd0[u*128 + j];
            float w2 = Wnd1[u*128 + v2];
            fma8(acc1, &xl[u][0], w1);
            fma8(acc2, &xl[128 + u*3 + m2][0], w2);
        }
        float b = bnd0[j];
        #pragma unroll
        for (int n = 0; n < 8; ++n) self_x[(size_t)(n0+n)*512 + j] = acc1[n] + b;
    } else {
        const int o1 = j - 128, v1 = o1/3, m1 = o1%3;
        for (int u = 0; u < 128; ++u){
            float w1 = Wnd1[u*128 + v1];
            float w2 = Wnd1[u*128 + v2];
            fma8(acc1, &xl[128 + u*3 + m1][0], w1);
            fma8(acc2, &xl[128 + u*3 + m2][0], w2);
        }
        #pragma unroll
        for (int n = 0; n < 8; ++n) self_x[(size_t)(n0+n)*512 + j] = acc1[n];
    }
    #pragma unroll
    for (int n = 0; n < 8; ++n) self_x[(size_t)(n0+n)*512 + j + 256] = acc2[n];
}

// ---------------- CSR build: count, scan, fill (arrays hosted in d_out) ----
__global__ __launch_bounds__(256) void k_count(
    const int* __restrict__ eidx, int* __restrict__ cnt)
{
    int e = blockIdx.x * 256 + threadIdx.x;
    if (e < EE){
        int d = eidx[e];
        if (d >= 0 && d < NN) atomicAdd(&cnt[d], 1);
    }
}

__global__ __launch_bounds__(256) void k_scan(
    const int* __restrict__ cnt, int* __restrict__ rowptr, int* __restrict__ cur)
{
    __shared__ int part[256];
    const int t = threadIdx.x;
    const int CHUNK = 79;             // 256*79 = 20224 >= 20000
    const int base = t * CHUNK;
    int s = 0;
    for (int i = 0; i < CHUNK; ++i){
        int idx = base + i;
        if (idx < NN) s += cnt[idx];
    }
    part[t] = s;
    __syncthreads();
    for (int off = 1; off < 256; off <<= 1){
        int v = (t >= off) ? part[t-off] : 0;
        __syncthreads();
        part[t] += v;
        __syncthreads();
    }
    int run = (t == 0) ? 0 : part[t-1];
    for (int i = 0; i < CHUNK; ++i){
        int idx = base + i;
        if (idx < NN){
            rowptr[idx] = run;
            cur[idx]    = run;
            run += cnt[idx];
        }
    }
    if (t == 255) rowptr[NN] = run;
}

__global__ __launch_bounds__(256) void k_fill(
    const int* __restrict__ eidx, int* __restrict__ cur, int2* __restrict__ ebuf,
    int* __restrict__ dstbuf)
{
    int e = blockIdx.x * 256 + threadIdx.x;
    if (e < EE){
        int dst = eidx[e];
        int src = eidx[EE + e];
        if (dst >= 0 && dst < NN){
            int pos = atomicAdd(&cur[dst], 1);
            if (pos >= 0 && pos < EE){
                ebuf[pos] = make_int2(e, src);
                dstbuf[pos] = dst;
            }
        }
    }
}

// ---------------- weight transpose: Wt[q][k] = W[k][q] ---------------------
__global__ __launch_bounds__(256) void k_wt(
    const float* __restrict__ Wf2, const float* __restrict__ Ws2,
    float* __restrict__ Wtf, float* __restrict__ Wts)
{
    int idx = blockIdx.x*256 + threadIdx.x;   // 0..16383 = q*32+k
    int q = idx >> 5, k = idx & 31;
    Wtf[idx] = Wf2[(size_t)k*512 + q];
    Wts[idx] = Ws2[(size_t)k*512 + q];
}

// ---------------- K3: edge features in CSR order -> fbuf, sbuf -------------
__global__ __launch_bounds__(256, 4) void k_edge_pre(
    const float* __restrict__ p1g, const float* __restrict__ sdst,
    const float* __restrict__ ea,
    const int2* __restrict__ ebuf, const int* __restrict__ dstbuf,
    const float* __restrict__ Wf1, const float* __restrict__ Ws1,
    float* __restrict__ fbuf, float* __restrict__ sbuf)
{
    __shared__ float ipw[4][128];
    const int tid  = threadIdx.x;
    const int wv   = tid >> 6, lane = tid & 63;
    const long e   = (long)blockIdx.x * 4 + wv;

    int2 pe = ebuf[e];
    if (!(pe.x >= 0 && pe.x < EE)) pe.x = 0;   // defensive (poison-safe)
    if (!(pe.y >= 0 && pe.y < NN)) pe.y = 0;
    int dst = dstbuf[e];
    if (!(dst >= 0 && dst < NN)) dst = 0;

    // channels u = 2*lane, 2*lane+1  ->  p1 row bytes [24*lane, 24*lane+24)
    const float* pd = p1g + (size_t)dst*384 + lane*6;
    const float* ps = p1g + (size_t)pe.y*384 + lane*6;
    const float2 d01 = *(const float2*)(pd);
    const float2 d23 = *(const float2*)(pd+2);
    const float2 d45 = *(const float2*)(pd+4);
    const float2 s01 = *(const float2*)(ps);
    const float2 s23 = *(const float2*)(ps+2);
    const float2 s45 = *(const float2*)(ps+4);
    const float ipa = (d01.x*s01.x + d01.y*s01.y + d23.x*s23.x) * (1.f/3.f);
    const float ipb = (d23.y*s23.y + d45.x*s45.x + d45.y*s45.y) * (1.f/3.f);
    *(float2*)&ipw[wv][lane*2] = make_float2(ipa, ipb);

    const int h = lane & 31;
    const float sdv = sdst[(size_t)dst*32 + h];   // broadcast per half-wave

    __syncthreads();

    // s-GEMV: half-wave u-split (lane>=32 -> u in [64,128))
    const int uh = (lane >> 5) * 64;
    float sA = 0.f, sB = 0.f;
    #pragma unroll 8
    for (int uu = 0; uu < 64; uu += 2){
        sA += ipw[wv][uh+uu]   * Ws1[(256+uh+uu)*32 + h];
        sB += ipw[wv][uh+uu+1] * Ws1[(257+uh+uu)*32 + h];
    }
    float s = sA + sB;
    s += __shfl_xor(s, 32);

    // f-GEMV: half-wave k-split (16 iters each)
    const int kh = (lane >> 5) * 16;
    const float* ear = ea + (size_t)pe.x*32 + kh;
    float f = 0.f;
    #pragma unroll 8
    for (int kk = 0; kk < 16; ++kk)
        f += ear[kk] * Wf1[(kh+kk)*32 + h];
    f += __shfl_xor(f, 32);

    if (lane < 32){
        sbuf[e*32 + h] = sspf(s + sdv);
        fbuf[e*32 + h] = sspf(f);
    }
}

// ---------------- fused edge GEMM + epilogue + segment reduction -----------
// Block = 64 CSR-ordered edges, 256 threads. Thread pair = channel c, half h.
// REGISTER-BLOCKED GEMM: edges processed in groups of 8 with k4 as the outer
// loop — the 4 weight float4s are loaded once per k4 (transient, 16 VGPRs,
// consumed immediately: nothing long-lived for the compiler to spill) and
// applied to 8 edges. Weight VMEM drops 8x vs per-edge reload. Long-lived
// state: 32 accumulators + 8 prefetched sx float2 — all constant-indexed in
// fully-unrolled loops. fb/sb stay in LDS (uniform-address broadcasts).
// sx gather: group-wise wave-private pipeline (8 coalesced float2/lane loads
// for group g+1 issued before group g's GEMM, landing in 8 LDS slots).
// Segment accumulation unchanged: interior direct-store, boundary atomicAdd.
__global__ __launch_bounds__(256) void k_edge_one(
    const float* __restrict__ fbuf, const float* __restrict__ sbuf,
    const float* __restrict__ self_x, const float* __restrict__ esh,
    const int2* __restrict__ ebuf, const int* __restrict__ dstbuf,
    const float* __restrict__ Wtf, const float* __restrict__ Wts,
    float* __restrict__ out)
{
    __shared__ float fbl[64][32];
    __shared__ float sbl[64][32];
    __shared__ float shl[64][4];
    __shared__ float sxl[4][8][128];   // wave-private: 8 edge slots x 512B
    __shared__ int   srcl[64], dl[64];

    const int tid = threadIdx.x;
    const int wv  = tid >> 6;          // wave id
    const int ln  = tid & 63;          // lane
    const int c   = tid >> 1;          // channel 0..127
    const int h   = tid & 1;           // half: 0 -> (w1,w2), 1 -> (w3,w4)
    const long e0 = (long)blockIdx.x * 64;
    const float IS3 = 0.57735026919f;

    // transposed weight row bases (each thread: 4 contiguous 128B rows)
    const int qA = 2*h*128 + c, qB = (2*h+1)*128 + c;
    const float4* pfA = (const float4*)(Wtf + (size_t)qA*32);
    const float4* pfB = (const float4*)(Wtf + (size_t)qB*32);
    const float4* psA = (const float4*)(Wts + (size_t)qA*32);
    const float4* psB = (const float4*)(Wts + (size_t)qB*32);

    if (tid < 64){
        int2 pe = ebuf[e0 + tid];
        if (!(pe.x >= 0 && pe.x < EE)) pe.x = 0;
        if (!(pe.y >= 0 && pe.y < NN)) pe.y = 0;
        int d = dstbuf[e0 + tid];
        if (!(d >= 0 && d < NN)) d = 0;
        srcl[tid] = pe.y; dl[tid] = d;
        ((float4*)shl)[tid] = ((const float4*)esh)[pe.x];
    }
    { // fbuf/sbuf CSR-contiguous: fully coalesced copy, 512 float4 each
        const float4* fsrc = (const float4*)(fbuf + (size_t)e0*32);
        const float4* ssrc = (const float4*)(sbuf + (size_t)e0*32);
        ((float4*)fbl)[tid]       = fsrc[tid];
        ((float4*)fbl)[tid + 256] = fsrc[tid + 256];
        ((float4*)sbl)[tid]       = ssrc[tid];
        ((float4*)sbl)[tid + 256] = ssrc[tid + 256];
    }
    __syncthreads();

    // neighbor dsts for boundary detection (block-uniform)
    const int dprev = (blockIdx.x == 0)    ? -1 : dstbuf[e0 - 1];
    const int dnext = (e0 + 64 < EE)       ? dstbuf[e0 + 64] : -1;

    // sx staging geometry: wave wv needs floats [32wv,32wv+32) (x0 part) and
    // [128+96wv, 128+96wv+96) (v part). lane<16 -> x0 float2, else v float2.
    const int goff = (ln < 16) ? (32*wv + 2*ln) : (128 + 96*wv + 2*(ln-16));
    const int loff = (ln < 16) ? (2*ln)         : (32 + 2*(ln-16));
    const int ci   = c & 31;           // channel index within wave

    // prologue: prefetch group 0 (8 coalesced float2 per lane)
    float2 r[8];
    #pragma unroll
    for (int ee = 0; ee < 8; ++ee)
        r[ee] = *(const float2*)(self_x + (size_t)srcl[ee]*512 + goff);

    float a0 = 0.f, a1 = 0.f;

    for (int eg = 0; eg < 8; ++eg){
        // stage current group into the wave's 8 LDS slots
        #pragma unroll
        for (int ee = 0; ee < 8; ++ee)
            *(float2*)&sxl[wv][ee][loff] = r[ee];
        // issue next group's loads (in flight across the GEMM below)
        if (eg < 7){
            #pragma unroll
            for (int ee = 0; ee < 8; ++ee)
                r[ee] = *(const float2*)(self_x +
                         (size_t)srcl[eg*8 + 8 + ee]*512 + goff);
        }

        // register-blocked GEMM: k4 outer, weights transient per k4
        float FA[8] = {0,0,0,0,0,0,0,0};
        float FB[8] = {0,0,0,0,0,0,0,0};
        float SA[8] = {0,0,0,0,0,0,0,0};
        float SB[8] = {0,0,0,0,0,0,0,0};
        #pragma unroll
        for (int k4 = 0; k4 < 8; ++k4){
            const float4 wfa = pfA[k4];
            const float4 wfb = pfB[k4];
            const float4 wsa = psA[k4];
            const float4 wsb = psB[k4];
            #pragma unroll
            for (int ee = 0; ee < 8; ++ee){
                const int e = eg*8 + ee;
                const float4 fb4 = *(const float4*)&fbl[e][k4*4];
                const float4 sb4 = *(const float4*)&sbl[e][k4*4];
                FA[ee] += fb4.x*wfa.x + fb4.y*wfa.y + fb4.z*wfa.z + fb4.w*wfa.w;
                FB[ee] += fb4.x*wfb.x + fb4.y*wfb.y + fb4.z*wfb.z + fb4.w*wfb.w;
                SA[ee] += sb4.x*wsa.x + sb4.y*wsa.y + sb4.z*wsa.z + sb4.w*wsa.w;
                SB[ee] += sb4.x*wsb.x + sb4.y*wsb.y + sb4.z*wsb.z + sb4.w*wsb.w;
            }
        }

        // per-edge epilogue + segment accumulation (in order)
        #pragma unroll
        for (int ee = 0; ee < 8; ++ee){
            const int e = eg*8 + ee;
            const float wA = FA[ee]*SA[ee], wB = FB[ee]*SB[ee];
            const float oA = __shfl_xor(wA, 1);
            const float oB = __shfl_xor(wB, 1);
            // h=0: w1=wA w2=wB w3=oA w4=oB ; h=1: w1=oA w2=oB w3=wA w4=wB
            const float w1 = h ? oA : wA;
            const float w2 = h ? oB : wB;
            const float w3 = h ? wA : oA;
            const float w4 = h ? wB : oB;

            const float x0c = sxl[wv][ee][ci];
            const float v0  = sxl[wv][ee][32 + 3*ci];
            const float v1  = sxl[wv][ee][32 + 3*ci + 1];
            const float v2  = sxl[wv][ee][32 + 3*ci + 2];

            const float4 sh = *(const float4*)&shl[e][0];
            const int dste = dl[e];

            const float dot = v0*sh.y + v1*sh.z + v2*sh.w;
            // h=0: a0 = out0[c],    a1 = out1[c][0]
            // h=1: a0 = out1[c][1], a1 = out1[c][2]
            const float caw = h ? w2 : w1;
            const float cf  = h ? sh.z : sh.x;
            const float cbw = h ? w3 : w4*IS3;
            const float cg  = h ? v1*sh.x : dot;
            a0 += caw*x0c*cf + cbw*cg;
            const float shm = h ? sh.w : sh.y;
            const float vm  = h ? v2 : v0;
            a1 += w2*x0c*shm + w3*vm*sh.x;

            if (e == 63 || dl[e+1] != dste){   // block-uniform segment end
                const bool openL = (a0 == a0) && (dl[0] == dste) && (dprev == dste) && (e - 63 < 0 ? true : true);
                // openL condition: this segment started at block begin AND
                // continues from previous block. Track via sstart == 0:
                (void)openL;
                float* orow = out + (size_t)dste*512;
                const int pos0 = h ? (128 + 3*c + 1) : c;
                const int pos1 = h ? (128 + 3*c + 2) : (128 + 3*c);
                const bool boundL = (dl[0] == dste) && (dprev == dste);
                const bool boundR = (e == 63) && (dnext == dste);
                if (boundL || boundR){
                    atomicAdd(orow + pos0, a0);
                    atomicAdd(orow + pos1, a1);
                } else {
                    orow[pos0] = a0;
                    orow[pos1] = a1;
                }
                a0 = 0.f; a1 = 0.f;
            }
        }
    }
}

// ---------------- K5: out linear + residual (in-place over d_out) ----------
__global__ __launch_bounds__(256) void k_post(
    const float* __restrict__ self_x, const float* __restrict__ x,
    const float* __restrict__ Wo0, const float* __restrict__ bo0,
    const float* __restrict__ Wo1,
    float* __restrict__ out)
{
    __shared__ float tl[512][8];
    const int tid = threadIdx.x;
    const int n0 = blockIdx.x * 8;

    for (int it = 0; it < 4; ++it){
        int idx = tid + 256*it;
        int node = idx >> 7, o4 = idx & 127;
        float4 a = ((const float4*)(out    + (size_t)(n0+node)*512))[o4];
        float4 b = ((const float4*)(self_x + (size_t)(n0+node)*512))[o4];
        tl[o4*4+0][node]=a.x+b.x; tl[o4*4+1][node]=a.y+b.y;
        tl[o4*4+2][node]=a.z+b.z; tl[o4*4+3][node]=a.w+b.w;
    }
    __syncthreads();

    const int j = tid;
    float acc1[8] = {0,0,0,0,0,0,0,0};
    float acc2[8] = {0,0,0,0,0,0,0,0};
    const int o2 = j + 128;
    const int v2 = o2/3, m2 = o2%3;
    if (j < 128){
        for (int u = 0; u < 128; ++u){
            float w1 = Wo0[u*128 + j];
            float w2 = Wo1[u*128 + v2];
            fma8(acc1, &tl[u][0], w1);
            fma8(acc2, &tl[128 + u*3 + m2][0], w2);
        }
        float b = bo0[j];
        #pragma unroll
        for (int n = 0; n < 8; ++n)
            out[(size_t)(n0+n)*512 + j] = acc1[n] + b + x[(size_t)(n0+n)*512 + j];
    } else {
        const int o1 = j - 128, v1 = o1/3, m1 = o1%3;
        for (int u = 0; u < 128; ++u){
            float w1 = Wo1[u*128 + v1];
            float w2 = Wo1[u*128 + v2];
            fma8(acc1, &tl[128 + u*3 + m1][0], w1);
            fma8(acc2, &tl[128 + u*3 + m2][0], w2);
        }
        #pragma unroll
        for (int n = 0; n < 8; ++n)
            out[(size_t)(n0+n)*512 + j] = acc1[n] + x[(size_t)(n0+n)*512 + j];
    }
    #pragma unroll
    for (int n = 0; n < 8; ++n)
        out[(size_t)(n0+n)*512 + j + 256] = acc2[n] + x[(size_t)(n0+n)*512 + j + 256];
}

// ---------------------------------------------------------------------------
extern "C" void kernel_launch(void* const* d_in, const int* in_sizes, int n_in,
                              void* d_out, int out_size, void* d_ws, size_t ws_size,
                              hipStream_t stream)
{
    const float* x    = (const float*)d_in[0];
    const float* esh  = (const float*)d_in[1];
    const float* ea   = (const float*)d_in[2];
    const int*   eidx = (const int*)  d_in[3];
    const float* Wp0  = (const float*)d_in[4];
    const float* bp0  = (const float*)d_in[5];
    const float* Wp1  = (const float*)d_in[6];
    const float* Wnd0 = (const float*)d_in[7];
    const float* bnd0 = (const float*)d_in[8];
    const float* Wnd1 = (const float*)d_in[9];
    const float* Wg1  = (const float*)d_in[10];
    const float* bg1  = (const float*)d_in[11];
    const float* Wg2  = (const float*)d_in[12];
    const float* bg2  = (const float*)d_in[13];
    const float* Wf1  = (const float*)d_in[14];
    const float* Wf2  = (const float*)d_in[15];
    const float* Ws1  = (const float*)d_in[16];
    const float* Ws2  = (const float*)d_in[17];
    const float* Wo0  = (const float*)d_in[18];
    const float* bo0  = (const float*)d_in[19];
    const float* Wo1  = (const float*)d_in[20];

    float* out  = (float*)d_out;
    float* ws   = (float*)d_ws;
    float* p1   = ws;                              // N*384 (dead after k_edge_pre)
    float* sdst = p1   + (size_t)NN*384;           // N*32
    float* sfx  = sdst + (size_t)NN*32;            // N*512
    float* fbuf = sfx  + (size_t)NN*512;           // E*32 (CSR-position order)
    float* sbuf = fbuf + (size_t)EE*32;            // E*32

    // CSR build arrays hosted in d_out (2.64 MB of 41 MB; out not needed yet)
    int*  dcnt  = (int*)d_out;                  // NN
    int*  dcur  = dcnt + NN;                    // NN
    int*  drow  = dcur + NN;                    // NN+1 (+3 pad for alignment)
    int2* debuf = (int2*)(drow + NN + 4);       // E int2 (byte 240016, 8-aligned)
    int*  ddst  = (int*)(debuf + EE);           // E int (contiguous after debuf)

    // CSR build first (needs only eidx)
    hipMemsetAsync(dcnt, 0, (size_t)NN*sizeof(int), stream);
    k_count <<<(EE+255)/256, 256, 0, stream>>>(eidx, dcnt);
    k_scan  <<<1, 256, 0, stream>>>(dcnt, drow, dcur);
    k_fill  <<<(EE+255)/256, 256, 0, stream>>>(eidx, dcur, debuf, ddst);

    k_pre     <<<NN/8, 256, 0, stream>>>(x, Wp0, bp0, Wp1, Ws1, p1, sdst);
    k_gate_nd <<<NN/8, 256, 0, stream>>>(x, Wg1, bg1, Wg2, bg2, Wnd0, bnd0, Wnd1, sfx);
    k_edge_pre<<<EE/4, 256, 0, stream>>>(p1, sdst, ea, debuf, ddst, Wf1, Ws1,
                                         fbuf, sbuf);

    // p1 now dead: CSR copy (ebuf+dstbuf, 2.4 MB) into its region, transposed
    // weights (256 KB) just after, then zero out for the scatter.
    int2*  ebuf2   = (int2*)ws;
    int*   dstbuf2 = (int*)ws + (size_t)2*EE;
    float* wtf     = ws + (size_t)3*EE;            // 512*32 floats
    float* wts     = wtf + 512*32;
    k_wt<<<64, 256, 0, stream>>>(Wf2, Ws2, wtf, wts);
    hipMemcpyAsync(ws, debuf, (size_t)3*EE*sizeof(int),
                   hipMemcpyDeviceToDevice, stream);
    hipMemsetAsync(out, 0, (size_t)NN*512*sizeof(float), stream);

    k_edge_one<<<EE/64, 256, 0, stream>>>(fbuf, sbuf, sfx, esh, ebuf2, dstbuf2,
                                          wtf, wts, out);

    k_post    <<<NN/8, 256, 0, stream>>>(sfx, x, Wo0, bo0, Wo1, out);
}

// Round 9
// 1229.040 us; speedup vs baseline: 3.0647x; 3.0647x over previous
//
#include <hip/hip_runtime.h>
#include <hip/hip_fp16.h>
#include <math.h>

#define NN 20000
#define EE 200000
// MUL=128, D=512, EDGE_ATTR=32, HID=32

__device__ __forceinline__ float sspf(float x){
    float sp = (x > 20.f) ? x : log1pf(expf(x));
    return sp - 0.69314718056f;
}

__device__ __forceinline__ void fma8(float* acc, const float* base, float w){
    const float4 a = ((const float4*)base)[0];
    const float4 b = ((const float4*)base)[1];
    acc[0]+=a.x*w; acc[1]+=a.y*w; acc[2]+=a.z*w; acc[3]+=a.w*w;
    acc[4]+=b.x*w; acc[5]+=b.y*w; acc[6]+=b.z*w; acc[7]+=b.w*w;
}

// ---------------- K1: pre irrep_linear -> p1, sdst (p0 consumed in-LDS) ----
__global__ __launch_bounds__(256) void k_pre(
    const float* __restrict__ x, const float* __restrict__ Wp0,
    const float* __restrict__ bp0, const float* __restrict__ Wp1,
    const float* __restrict__ Ws1,
    float* __restrict__ p1, float* __restrict__ sdst)
{
    __shared__ float xl[512][8];    // transposed [feature][node]
    __shared__ float p0l[8][128];
    const int tid = threadIdx.x;
    const int n0 = blockIdx.x * 8;

    for (int it = 0; it < 4; ++it){
        int idx = tid + 256*it;           // 0..1023 float4 slots
        int node = idx >> 7, o4 = idx & 127;
        float4 v = ((const float4*)(x + (size_t)(n0+node)*512))[o4];
        xl[o4*4+0][node]=v.x; xl[o4*4+1][node]=v.y;
        xl[o4*4+2][node]=v.z; xl[o4*4+3][node]=v.w;
    }
    __syncthreads();

    const int j = tid;
    float acc1[8] = {0,0,0,0,0,0,0,0};
    float acc2[8] = {0,0,0,0,0,0,0,0};
    const int o2 = j + 128;               // p1-index in [128,384)
    const int v2 = o2/3, m2 = o2%3;

    if (j < 128){
        for (int u = 0; u < 128; ++u){
            float w1 = Wp0[u*128 + j];
            float w2 = Wp1[u*128 + v2];
            fma8(acc1, &xl[u][0], w1);
            fma8(acc2, &xl[128 + u*3 + m2][0], w2);
        }
        float b = bp0[j];
        #pragma unroll
        for (int n = 0; n < 8; ++n) p0l[n][j] = acc1[n] + b;
    } else {
        const int o1 = j - 128, v1 = o1/3, m1 = o1%3;
        for (int u = 0; u < 128; ++u){
            float w1 = Wp1[u*128 + v1];
            float w2 = Wp1[u*128 + v2];
            fma8(acc1, &xl[128 + u*3 + m1][0], w1);
            fma8(acc2, &xl[128 + u*3 + m2][0], w2);
        }
        #pragma unroll
        for (int n = 0; n < 8; ++n) p1[(size_t)(n0+n)*384 + (j-128)] = acc1[n];
    }
    #pragma unroll
    for (int n = 0; n < 8; ++n) p1[(size_t)(n0+n)*384 + o2] = acc2[n];
    __syncthreads();

    // sdst = p0 @ (Ws1[0:128] + Ws1[128:256])  (the dst-only part of s0@W_s1)
    {
        int n = tid >> 5, h = tid & 31;
        float s = 0.f;
        for (int u = 0; u < 128; ++u){
            float wc = Ws1[u*32 + h] + Ws1[(128+u)*32 + h];
            s += p0l[n][u] * wc;
        }
        sdst[(size_t)(n0+n)*32 + h] = s;
    }
}

// ---------------- K2: gate + node irrep_linear -> self_x -------------------
__global__ __launch_bounds__(256) void k_gate_nd(
    const float* __restrict__ x,
    const float* __restrict__ Wg1, const float* __restrict__ bg1,
    const float* __restrict__ Wg2, const float* __restrict__ bg2,
    const float* __restrict__ Wnd0, const float* __restrict__ bnd0,
    const float* __restrict__ Wnd1,
    float* __restrict__ self_x)
{
    __shared__ float xl[512][8];
    __shared__ float tl[256][8];   // t, then reused for g
    __shared__ float hl[256][8];
    const int tid = threadIdx.x;
    const int n0 = blockIdx.x * 8;

    for (int it = 0; it < 4; ++it){
        int idx = tid + 256*it;
        int node = idx >> 7, o4 = idx & 127;
        float4 v = ((const float4*)(x + (size_t)(n0+node)*512))[o4];
        xl[o4*4+0][node]=v.x; xl[o4*4+1][node]=v.y;
        xl[o4*4+2][node]=v.z; xl[o4*4+3][node]=v.w;
    }
    __syncthreads();

    { // t = [x0, n1]
        int jj = tid;
        if (jj < 128){
            #pragma unroll
            for (int n = 0; n < 8; ++n) tl[jj][n] = xl[jj][n];
        } else {
            int u = jj - 128;
            #pragma unroll
            for (int n = 0; n < 8; ++n){
                float a = xl[128+u*3][n], b = xl[128+u*3+1][n], c = xl[128+u*3+2][n];
                tl[jj][n] = sqrtf((a*a + b*b + c*c) * (1.f/3.f));
            }
        }
    }
    __syncthreads();

    { // h = silu(t @ Wg1 + bg1)
        float acc[8] = {0,0,0,0,0,0,0,0};
        for (int k = 0; k < 256; ++k){
            float w = Wg1[k*256 + tid];
            fma8(acc, &tl[k][0], w);
        }
        float b = bg1[tid];
        #pragma unroll
        for (int n = 0; n < 8; ++n){
            float v = acc[n] + b;
            hl[tid][n] = v / (1.f + expf(-v));
        }
    }
    __syncthreads();

    { // g = h @ Wg2 + bg2  (stored into tl; tl is dead after the barrier)
        float acc[8] = {0,0,0,0,0,0,0,0};
        for (int k = 0; k < 256; ++k){
            float w = Wg2[k*256 + tid];
            fma8(acc, &hl[k][0], w);
        }
        float b = bg2[tid];
        #pragma unroll
        for (int n = 0; n < 8; ++n) tl[tid][n] = acc[n] + b;
    }
    __syncthreads();

    { // xg in-place into xl
        int jj = tid;
        if (jj < 128){
            #pragma unroll
            for (int n = 0; n < 8; ++n) xl[jj][n] = tl[jj][n];
        } else {
            int u = jj - 128;
            #pragma unroll
            for (int n = 0; n < 8; ++n){
                float g1 = tl[128+u][n];
                xl[128+u*3  ][n] *= g1;
                xl[128+u*3+1][n] *= g1;
                xl[128+u*3+2][n] *= g1;
            }
        }
    }
    __syncthreads();

    // nd irrep_linear
    const int j = tid;
    float acc1[8] = {0,0,0,0,0,0,0,0};
    float acc2[8] = {0,0,0,0,0,0,0,0};
    const int o2 = j + 128;
    const int v2 = o2/3, m2 = o2%3;
    if (j < 128){
        for (int u = 0; u < 128; ++u){
            float w1 = Wnd0[u*128 + j];
            float w2 = Wnd1[u*128 + v2];
            fma8(acc1, &xl[u][0], w1);
            fma8(acc2, &xl[128 + u*3 + m2][0], w2);
        }
        float b = bnd0[j];
        #pragma unroll
        for (int n = 0; n < 8; ++n) self_x[(size_t)(n0+n)*512 + j] = acc1[n] + b;
    } else {
        const int o1 = j - 128, v1 = o1/3, m1 = o1%3;
        for (int u = 0; u < 128; ++u){
            float w1 = Wnd1[u*128 + v1];
            float w2 = Wnd1[u*128 + v2];
            fma8(acc1, &xl[128 + u*3 + m1][0], w1);
            fma8(acc2, &xl[128 + u*3 + m2][0], w2);
        }
        #pragma unroll
        for (int n = 0; n < 8; ++n) self_x[(size_t)(n0+n)*512 + j] = acc1[n];
    }
    #pragma unroll
    for (int n = 0; n < 8; ++n) self_x[(size_t)(n0+n)*512 + j + 256] = acc2[n];
}

// ---------------- CSR build: count, scan, fill (arrays hosted in d_out) ----
__global__ __launch_bounds__(256) void k_count(
    const int* __restrict__ eidx, int* __restrict__ cnt)
{
    int e = blockIdx.x * 256 + threadIdx.x;
    if (e < EE){
        int d = eidx[e];
        if (d >= 0 && d < NN) atomicAdd(&cnt[d], 1);
    }
}

__global__ __launch_bounds__(256) void k_scan(
    const int* __restrict__ cnt, int* __restrict__ rowptr, int* __restrict__ cur)
{
    __shared__ int part[256];
    const int t = threadIdx.x;
    const int CHUNK = 79;             // 256*79 = 20224 >= 20000
    const int base = t * CHUNK;
    int s = 0;
    for (int i = 0; i < CHUNK; ++i){
        int idx = base + i;
        if (idx < NN) s += cnt[idx];
    }
    part[t] = s;
    __syncthreads();
    for (int off = 1; off < 256; off <<= 1){
        int v = (t >= off) ? part[t-off] : 0;
        __syncthreads();
        part[t] += v;
        __syncthreads();
    }
    int run = (t == 0) ? 0 : part[t-1];
    for (int i = 0; i < CHUNK; ++i){
        int idx = base + i;
        if (idx < NN){
            rowptr[idx] = run;
            cur[idx]    = run;
            run += cnt[idx];
        }
    }
    if (t == 255) rowptr[NN] = run;
}

__global__ __launch_bounds__(256) void k_fill(
    const int* __restrict__ eidx, int* __restrict__ cur, int2* __restrict__ ebuf,
    int* __restrict__ dstbuf)
{
    int e = blockIdx.x * 256 + threadIdx.x;
    if (e < EE){
        int dst = eidx[e];
        int src = eidx[EE + e];
        if (dst >= 0 && dst < NN){
            int pos = atomicAdd(&cur[dst], 1);
            if (pos >= 0 && pos < EE){
                ebuf[pos] = make_int2(e, src);
                dstbuf[pos] = dst;
            }
        }
    }
}

// ---------------- weight transpose: Wt[q][k] = W[k][q] ---------------------
__global__ __launch_bounds__(256) void k_wt(
    const float* __restrict__ Wf2, const float* __restrict__ Ws2,
    float* __restrict__ Wtf, float* __restrict__ Wts)
{
    int idx = blockIdx.x*256 + threadIdx.x;   // 0..16383 = q*32+k
    int q = idx >> 5, k = idx & 31;
    Wtf[idx] = Wf2[(size_t)k*512 + q];
    Wts[idx] = Ws2[(size_t)k*512 + q];
}

// ---------------- K3: edge features in CSR order -> fbuf, sbuf -------------
__global__ __launch_bounds__(256, 4) void k_edge_pre(
    const float* __restrict__ p1g, const float* __restrict__ sdst,
    const float* __restrict__ ea,
    const int2* __restrict__ ebuf, const int* __restrict__ dstbuf,
    const float* __restrict__ Wf1, const float* __restrict__ Ws1,
    float* __restrict__ fbuf, float* __restrict__ sbuf)
{
    __shared__ float ipw[4][128];
    const int tid  = threadIdx.x;
    const int wv   = tid >> 6, lane = tid & 63;
    const long e   = (long)blockIdx.x * 4 + wv;

    int2 pe = ebuf[e];
    if (!(pe.x >= 0 && pe.x < EE)) pe.x = 0;   // defensive (poison-safe)
    if (!(pe.y >= 0 && pe.y < NN)) pe.y = 0;
    int dst = dstbuf[e];
    if (!(dst >= 0 && dst < NN)) dst = 0;

    // channels u = 2*lane, 2*lane+1  ->  p1 row bytes [24*lane, 24*lane+24)
    const float* pd = p1g + (size_t)dst*384 + lane*6;
    const float* ps = p1g + (size_t)pe.y*384 + lane*6;
    const float2 d01 = *(const float2*)(pd);
    const float2 d23 = *(const float2*)(pd+2);
    const float2 d45 = *(const float2*)(pd+4);
    const float2 s01 = *(const float2*)(ps);
    const float2 s23 = *(const float2*)(ps+2);
    const float2 s45 = *(const float2*)(ps+4);
    const float ipa = (d01.x*s01.x + d01.y*s01.y + d23.x*s23.x) * (1.f/3.f);
    const float ipb = (d23.y*s23.y + d45.x*s45.x + d45.y*s45.y) * (1.f/3.f);
    *(float2*)&ipw[wv][lane*2] = make_float2(ipa, ipb);

    const int h = lane & 31;
    const float sdv = sdst[(size_t)dst*32 + h];   // broadcast per half-wave

    __syncthreads();

    // s-GEMV: half-wave u-split (lane>=32 -> u in [64,128))
    const int uh = (lane >> 5) * 64;
    float sA = 0.f, sB = 0.f;
    #pragma unroll 8
    for (int uu = 0; uu < 64; uu += 2){
        sA += ipw[wv][uh+uu]   * Ws1[(256+uh+uu)*32 + h];
        sB += ipw[wv][uh+uu+1] * Ws1[(257+uh+uu)*32 + h];
    }
    float s = sA + sB;
    s += __shfl_xor(s, 32);

    // f-GEMV: half-wave k-split (16 iters each)
    const int kh = (lane >> 5) * 16;
    const float* ear = ea + (size_t)pe.x*32 + kh;
    float f = 0.f;
    #pragma unroll 8
    for (int kk = 0; kk < 16; ++kk)
        f += ear[kk] * Wf1[(kh+kk)*32 + h];
    f += __shfl_xor(f, 32);

    if (lane < 32){
        sbuf[e*32 + h] = sspf(s + sdv);
        fbuf[e*32 + h] = sspf(f);
    }
}

// ---------------- fused edge GEMM + epilogue + segment reduction -----------
// R5/R6 known-good skeleton + minimal PAIR blocking (E=2). Block = 64 CSR
// edges, 256 threads; thread pair = channel c, half h. Per pair of edges the
// k4-outer loop loads 4 weight float4s once (TRANSIENT — consumed
// immediately, exactly the pattern that compiled clean at VGPR 84) and
// applies them to both edges: weight VMEM instr per edge halves (32 -> 16).
// All long-lived state is named scalars (8 accs, 8 sx floats, 2 float2-pair
// prefetch) — constant-indexed, nothing to spill. fb/sb from LDS staging
// (uniform broadcasts); sx via 2-slot wave-private pipeline; segment logic
// is R5's proven sstart tracking.
__global__ __launch_bounds__(256) void k_edge_one(
    const float* __restrict__ fbuf, const float* __restrict__ sbuf,
    const float* __restrict__ self_x, const float* __restrict__ esh,
    const int2* __restrict__ ebuf, const int* __restrict__ dstbuf,
    const float* __restrict__ Wtf, const float* __restrict__ Wts,
    float* __restrict__ out)
{
    __shared__ float fbl[64][32];
    __shared__ float sbl[64][32];
    __shared__ float shl[64][4];
    __shared__ float sxl[4][2][128];   // wave-private, 2 edge slots
    __shared__ int   srcl[64], dl[64];

    const int tid = threadIdx.x;
    const int wv  = tid >> 6;          // wave id
    const int ln  = tid & 63;          // lane
    const int c   = tid >> 1;          // channel 0..127
    const int h   = tid & 1;           // half: 0 -> (w1,w2), 1 -> (w3,w4)
    const long e0 = (long)blockIdx.x * 64;
    const float IS3 = 0.57735026919f;

    // transposed weight row bases (each thread: 4 contiguous 128B rows)
    const int qA = 2*h*128 + c, qB = (2*h+1)*128 + c;
    const float4* pfA = (const float4*)(Wtf + (size_t)qA*32);
    const float4* pfB = (const float4*)(Wtf + (size_t)qB*32);
    const float4* psA = (const float4*)(Wts + (size_t)qA*32);
    const float4* psB = (const float4*)(Wts + (size_t)qB*32);

    if (tid < 64){
        int2 pe = ebuf[e0 + tid];
        if (!(pe.x >= 0 && pe.x < EE)) pe.x = 0;
        if (!(pe.y >= 0 && pe.y < NN)) pe.y = 0;
        int d = dstbuf[e0 + tid];
        if (!(d >= 0 && d < NN)) d = 0;
        srcl[tid] = pe.y; dl[tid] = d;
        ((float4*)shl)[tid] = ((const float4*)esh)[pe.x];
    }
    { // fbuf/sbuf CSR-contiguous: fully coalesced copy, 512 float4 each
        const float4* fsrc = (const float4*)(fbuf + (size_t)e0*32);
        const float4* ssrc = (const float4*)(sbuf + (size_t)e0*32);
        ((float4*)fbl)[tid]       = fsrc[tid];
        ((float4*)fbl)[tid + 256] = fsrc[tid + 256];
        ((float4*)sbl)[tid]       = ssrc[tid];
        ((float4*)sbl)[tid + 256] = ssrc[tid + 256];
    }
    __syncthreads();

    // neighbor dsts for boundary detection (block-uniform)
    const int dprev = (blockIdx.x == 0)    ? -1 : dstbuf[e0 - 1];
    const int dnext = (e0 + 64 < EE)       ? dstbuf[e0 + 64] : -1;

    // sx staging geometry: wave wv needs floats [32wv,32wv+32) (x0 part) and
    // [128+96wv, 128+96wv+96) (v part). lane<16 -> x0 float2, else v float2.
    const int goff = (ln < 16) ? (32*wv + 2*ln) : (128 + 96*wv + 2*(ln-16));
    const int loff = (ln < 16) ? (2*ln)         : (32 + 2*(ln-16));
    const int ci   = c & 31;           // channel index within wave

    // prologue: slots <- pair0; rA = pair1, rB = pair2 (in flight)
    {
        float2 t0 = *(const float2*)(self_x + (size_t)srcl[0]*512 + goff);
        float2 t1 = *(const float2*)(self_x + (size_t)srcl[1]*512 + goff);
        *(float2*)&sxl[wv][0][loff] = t0;
        *(float2*)&sxl[wv][1][loff] = t1;
    }
    float2 rA0 = *(const float2*)(self_x + (size_t)srcl[2]*512 + goff);
    float2 rA1 = *(const float2*)(self_x + (size_t)srcl[3]*512 + goff);
    float2 rB0 = *(const float2*)(self_x + (size_t)srcl[4]*512 + goff);
    float2 rB1 = *(const float2*)(self_x + (size_t)srcl[5]*512 + goff);

    float a0 = 0.f, a1 = 0.f;
    int sstart = 0;

    for (int p = 0; p < 32; ++p){
        const int eA = 2*p, eB = 2*p + 1;

        // read pair p's sx values into registers (2-lane broadcasts)
        const float x0cA = sxl[wv][0][ci];
        const float v0A  = sxl[wv][0][32 + 3*ci];
        const float v1A  = sxl[wv][0][32 + 3*ci + 1];
        const float v2A  = sxl[wv][0][32 + 3*ci + 2];
        const float x0cB = sxl[wv][1][ci];
        const float v0B  = sxl[wv][1][32 + 3*ci];
        const float v1B  = sxl[wv][1][32 + 3*ci + 1];
        const float v2B  = sxl[wv][1][32 + 3*ci + 2];

        // rotate pipeline (same-wave DS ordering: reads above complete first)
        if (p < 31){
            *(float2*)&sxl[wv][0][loff] = rA0;
            *(float2*)&sxl[wv][1][loff] = rA1;
            rA0 = rB0; rA1 = rB1;
            if (p < 29){
                rB0 = *(const float2*)(self_x + (size_t)srcl[2*p+6]*512 + goff);
                rB1 = *(const float2*)(self_x + (size_t)srcl[2*p+7]*512 + goff);
            }
        }

        // pair GEMM: k4 outer, transient weights shared by both edges
        float FA0=0.f, FB0=0.f, SA0=0.f, SB0=0.f;
        float FA1=0.f, FB1=0.f, SA1=0.f, SB1=0.f;
        #pragma unroll
        for (int k4 = 0; k4 < 8; ++k4){
            const float4 wfa = pfA[k4];
            const float4 wfb = pfB[k4];
            const float4 wsa = psA[k4];
            const float4 wsb = psB[k4];
            const float4 fA = *(const float4*)&fbl[eA][k4*4];
            const float4 sA = *(const float4*)&sbl[eA][k4*4];
            const float4 fB = *(const float4*)&fbl[eB][k4*4];
            const float4 sB = *(const float4*)&sbl[eB][k4*4];
            FA0 += fA.x*wfa.x + fA.y*wfa.y + fA.z*wfa.z + fA.w*wfa.w;
            FB0 += fA.x*wfb.x + fA.y*wfb.y + fA.z*wfb.z + fA.w*wfb.w;
            SA0 += sA.x*wsa.x + sA.y*wsa.y + sA.z*wsa.z + sA.w*wsa.w;
            SB0 += sA.x*wsb.x + sA.y*wsb.y + sA.z*wsb.z + sA.w*wsb.w;
            FA1 += fB.x*wfa.x + fB.y*wfa.y + fB.z*wfa.z + fB.w*wfa.w;
            FB1 += fB.x*wfb.x + fB.y*wfb.y + fB.z*wfb.z + fB.w*wfb.w;
            SA1 += sB.x*wsa.x + sB.y*wsa.y + sB.z*wsa.z + sB.w*wsa.w;
            SB1 += sB.x*wsb.x + sB.y*wsb.y + sB.z*wsb.z + sB.w*wsb.w;
        }

        // per-edge epilogue + segment accumulation (in order)
        #pragma unroll
        for (int ee = 0; ee < 2; ++ee){
            const int e = 2*p + ee;
            const float wA = ee ? FA1*SA1 : FA0*SA0;
            const float wB = ee ? FB1*SB1 : FB0*SB0;
            const float oA = __shfl_xor(wA, 1);
            const float oB = __shfl_xor(wB, 1);
            // h=0: w1=wA w2=wB w3=oA w4=oB ; h=1: w1=oA w2=oB w3=wA w4=wB
            const float w1 = h ? oA : wA;
            const float w2 = h ? oB : wB;
            const float w3 = h ? wA : oA;
            const float w4 = h ? wB : oB;

            const float x0c = ee ? x0cB : x0cA;
            const float v0  = ee ? v0B : v0A;
            const float v1  = ee ? v1B : v1A;
            const float v2  = ee ? v2B : v2A;

            const float4 sh = *(const float4*)&shl[e][0];
            const int dste = dl[e];

            const float dot = v0*sh.y + v1*sh.z + v2*sh.w;
            // h=0: a0 = out0[c],    a1 = out1[c][0]
            // h=1: a0 = out1[c][1], a1 = out1[c][2]
            const float caw = h ? w2 : w1;
            const float cf  = h ? sh.z : sh.x;
            const float cbw = h ? w3 : w4*IS3;
            const float cg  = h ? v1*sh.x : dot;
            a0 += caw*x0c*cf + cbw*cg;
            const float shm = h ? sh.w : sh.y;
            const float vm  = h ? v2 : v0;
            a1 += w2*x0c*shm + w3*vm*sh.x;

            if (e == 63 || dl[e+1] != dste){   // block-uniform segment end
                const bool openL = (sstart == 0) && (dprev == dste);
                const bool openR = (e == 63) && (dnext == dste);
                float* orow = out + (size_t)dste*512;
                const int pos0 = h ? (128 + 3*c + 1) : c;
                const int pos1 = h ? (128 + 3*c + 2) : (128 + 3*c);
                if (openL || openR){
                    atomicAdd(orow + pos0, a0);
                    atomicAdd(orow + pos1, a1);
                } else {
                    orow[pos0] = a0;
                    orow[pos1] = a1;
                }
                a0 = 0.f; a1 = 0.f; sstart = e + 1;
            }
        }
    }
}

// ---------------- K5: out linear + residual (in-place over d_out) ----------
__global__ __launch_bounds__(256) void k_post(
    const float* __restrict__ self_x, const float* __restrict__ x,
    const float* __restrict__ Wo0, const float* __restrict__ bo0,
    const float* __restrict__ Wo1,
    float* __restrict__ out)
{
    __shared__ float tl[512][8];
    const int tid = threadIdx.x;
    const int n0 = blockIdx.x * 8;

    for (int it = 0; it < 4; ++it){
        int idx = tid + 256*it;
        int node = idx >> 7, o4 = idx & 127;
        float4 a = ((const float4*)(out    + (size_t)(n0+node)*512))[o4];
        float4 b = ((const float4*)(self_x + (size_t)(n0+node)*512))[o4];
        tl[o4*4+0][node]=a.x+b.x; tl[o4*4+1][node]=a.y+b.y;
        tl[o4*4+2][node]=a.z+b.z; tl[o4*4+3][node]=a.w+b.w;
    }
    __syncthreads();

    const int j = tid;
    float acc1[8] = {0,0,0,0,0,0,0,0};
    float acc2[8] = {0,0,0,0,0,0,0,0};
    const int o2 = j + 128;
    const int v2 = o2/3, m2 = o2%3;
    if (j < 128){
        for (int u = 0; u < 128; ++u){
            float w1 = Wo0[u*128 + j];
            float w2 = Wo1[u*128 + v2];
            fma8(acc1, &tl[u][0], w1);
            fma8(acc2, &tl[128 + u*3 + m2][0], w2);
        }
        float b = bo0[j];
        #pragma unroll
        for (int n = 0; n < 8; ++n)
            out[(size_t)(n0+n)*512 + j] = acc1[n] + b + x[(size_t)(n0+n)*512 + j];
    } else {
        const int o1 = j - 128, v1 = o1/3, m1 = o1%3;
        for (int u = 0; u < 128; ++u){
            float w1 = Wo1[u*128 + v1];
            float w2 = Wo1[u*128 + v2];
            fma8(acc1, &tl[128 + u*3 + m1][0], w1);
            fma8(acc2, &tl[128 + u*3 + m2][0], w2);
        }
        #pragma unroll
        for (int n = 0; n < 8; ++n)
            out[(size_t)(n0+n)*512 + j] = acc1[n] + x[(size_t)(n0+n)*512 + j];
    }
    #pragma unroll
    for (int n = 0; n < 8; ++n)
        out[(size_t)(n0+n)*512 + j + 256] = acc2[n] + x[(size_t)(n0+n)*512 + j + 256];
}

// ---------------------------------------------------------------------------
extern "C" void kernel_launch(void* const* d_in, const int* in_sizes, int n_in,
                              void* d_out, int out_size, void* d_ws, size_t ws_size,
                              hipStream_t stream)
{
    const float* x    = (const float*)d_in[0];
    const float* esh  = (const float*)d_in[1];
    const float* ea   = (const float*)d_in[2];
    const int*   eidx = (const int*)  d_in[3];
    const float* Wp0  = (const float*)d_in[4];
    const float* bp0  = (const float*)d_in[5];
    const float* Wp1  = (const float*)d_in[6];
    const float* Wnd0 = (const float*)d_in[7];
    const float* bnd0 = (const float*)d_in[8];
    const float* Wnd1 = (const float*)d_in[9];
    const float* Wg1  = (const float*)d_in[10];
    const float* bg1  = (const float*)d_in[11];
    const float* Wg2  = (const float*)d_in[12];
    const float* bg2  = (const float*)d_in[13];
    const float* Wf1  = (const float*)d_in[14];
    const float* Wf2  = (const float*)d_in[15];
    const float* Ws1  = (const float*)d_in[16];
    const float* Ws2  = (const float*)d_in[17];
    const float* Wo0  = (const float*)d_in[18];
    const float* bo0  = (const float*)d_in[19];
    const float* Wo1  = (const float*)d_in[20];

    float* out  = (float*)d_out;
    float* ws   = (float*)d_ws;
    float* p1   = ws;                              // N*384 (dead after k_edge_pre)
    float* sdst = p1   + (size_t)NN*384;           // N*32
    float* sfx  = sdst + (size_t)NN*32;            // N*512
    float* fbuf = sfx  + (size_t)NN*512;           // E*32 (CSR-position order)
    float* sbuf = fbuf + (size_t)EE*32;            // E*32

    // CSR build arrays hosted in d_out (2.64 MB of 41 MB; out not needed yet)
    int*  dcnt  = (int*)d_out;                  // NN
    int*  dcur  = dcnt + NN;                    // NN
    int*  drow  = dcur + NN;                    // NN+1 (+3 pad for alignment)
    int2* debuf = (int2*)(drow + NN + 4);       // E int2 (byte 240016, 8-aligned)
    int*  ddst  = (int*)(debuf + EE);           // E int (contiguous after debuf)

    // CSR build first (needs only eidx)
    hipMemsetAsync(dcnt, 0, (size_t)NN*sizeof(int), stream);
    k_count <<<(EE+255)/256, 256, 0, stream>>>(eidx, dcnt);
    k_scan  <<<1, 256, 0, stream>>>(dcnt, drow, dcur);
    k_fill  <<<(EE+255)/256, 256, 0, stream>>>(eidx, dcur, debuf, ddst);

    k_pre     <<<NN/8, 256, 0, stream>>>(x, Wp0, bp0, Wp1, Ws1, p1, sdst);
    k_gate_nd <<<NN/8, 256, 0, stream>>>(x, Wg1, bg1, Wg2, bg2, Wnd0, bnd0, Wnd1, sfx);
    k_edge_pre<<<EE/4, 256, 0, stream>>>(p1, sdst, ea, debuf, ddst, Wf1, Ws1,
                                         fbuf, sbuf);

    // p1 now dead: CSR copy (ebuf+dstbuf, 2.4 MB) into its region, transposed
    // weights (256 KB) just after, then zero out for the scatter.
    int2*  ebuf2   = (int2*)ws;
    int*   dstbuf2 = (int*)ws + (size_t)2*EE;
    float* wtf     = ws + (size_t)3*EE;            // 512*32 floats
    float* wts     = wtf + 512*32;
    k_wt<<<64, 256, 0, stream>>>(Wf2, Ws2, wtf, wts);
    hipMemcpyAsync(ws, debuf, (size_t)3*EE*sizeof(int),
                   hipMemcpyDeviceToDevice, stream);
    hipMemsetAsync(out, 0, (size_t)NN*512*sizeof(float), stream);

    k_edge_one<<<EE/64, 256, 0, stream>>>(fbuf, sbuf, sfx, esh, ebuf2, dstbuf2,
                                          wtf, wts, out);

    k_post    <<<NN/8, 256, 0, stream>>>(sfx, x, Wo0, bo0, Wo1, out);
}

// Round 10
// 1174.646 us; speedup vs baseline: 3.2066x; 1.0463x over previous
//
#include <hip/hip_runtime.h>
#include <hip/hip_fp16.h>
#include <math.h>

#define NN 20000
#define EE 200000
// MUL=128, D=512, EDGE_ATTR=32, HID=32

__device__ __forceinline__ float sspf(float x){
    float sp = (x > 20.f) ? x : log1pf(expf(x));
    return sp - 0.69314718056f;
}

__device__ __forceinline__ void fma8(float* acc, const float* base, float w){
    const float4 a = ((const float4*)base)[0];
    const float4 b = ((const float4*)base)[1];
    acc[0]+=a.x*w; acc[1]+=a.y*w; acc[2]+=a.z*w; acc[3]+=a.w*w;
    acc[4]+=b.x*w; acc[5]+=b.y*w; acc[6]+=b.z*w; acc[7]+=b.w*w;
}

// ---------------- K1: pre irrep_linear -> p1, sdst (p0 consumed in-LDS) ----
__global__ __launch_bounds__(256) void k_pre(
    const float* __restrict__ x, const float* __restrict__ Wp0,
    const float* __restrict__ bp0, const float* __restrict__ Wp1,
    const float* __restrict__ Ws1,
    float* __restrict__ p1, float* __restrict__ sdst)
{
    __shared__ float xl[512][8];    // transposed [feature][node]
    __shared__ float p0l[8][128];
    const int tid = threadIdx.x;
    const int n0 = blockIdx.x * 8;

    for (int it = 0; it < 4; ++it){
        int idx = tid + 256*it;           // 0..1023 float4 slots
        int node = idx >> 7, o4 = idx & 127;
        float4 v = ((const float4*)(x + (size_t)(n0+node)*512))[o4];
        xl[o4*4+0][node]=v.x; xl[o4*4+1][node]=v.y;
        xl[o4*4+2][node]=v.z; xl[o4*4+3][node]=v.w;
    }
    __syncthreads();

    const int j = tid;
    float acc1[8] = {0,0,0,0,0,0,0,0};
    float acc2[8] = {0,0,0,0,0,0,0,0};
    const int o2 = j + 128;               // p1-index in [128,384)
    const int v2 = o2/3, m2 = o2%3;

    if (j < 128){
        for (int u = 0; u < 128; ++u){
            float w1 = Wp0[u*128 + j];
            float w2 = Wp1[u*128 + v2];
            fma8(acc1, &xl[u][0], w1);
            fma8(acc2, &xl[128 + u*3 + m2][0], w2);
        }
        float b = bp0[j];
        #pragma unroll
        for (int n = 0; n < 8; ++n) p0l[n][j] = acc1[n] + b;
    } else {
        const int o1 = j - 128, v1 = o1/3, m1 = o1%3;
        for (int u = 0; u < 128; ++u){
            float w1 = Wp1[u*128 + v1];
            float w2 = Wp1[u*128 + v2];
            fma8(acc1, &xl[128 + u*3 + m1][0], w1);
            fma8(acc2, &xl[128 + u*3 + m2][0], w2);
        }
        #pragma unroll
        for (int n = 0; n < 8; ++n) p1[(size_t)(n0+n)*384 + (j-128)] = acc1[n];
    }
    #pragma unroll
    for (int n = 0; n < 8; ++n) p1[(size_t)(n0+n)*384 + o2] = acc2[n];
    __syncthreads();

    // sdst = p0 @ (Ws1[0:128] + Ws1[128:256])  (the dst-only part of s0@W_s1)
    {
        int n = tid >> 5, h = tid & 31;
        float s = 0.f;
        for (int u = 0; u < 128; ++u){
            float wc = Ws1[u*32 + h] + Ws1[(128+u)*32 + h];
            s += p0l[n][u] * wc;
        }
        sdst[(size_t)(n0+n)*32 + h] = s;
    }
}

// ---------------- K2: gate + node irrep_linear -> self_x -------------------
__global__ __launch_bounds__(256) void k_gate_nd(
    const float* __restrict__ x,
    const float* __restrict__ Wg1, const float* __restrict__ bg1,
    const float* __restrict__ Wg2, const float* __restrict__ bg2,
    const float* __restrict__ Wnd0, const float* __restrict__ bnd0,
    const float* __restrict__ Wnd1,
    float* __restrict__ self_x)
{
    __shared__ float xl[512][8];
    __shared__ float tl[256][8];   // t, then reused for g
    __shared__ float hl[256][8];
    const int tid = threadIdx.x;
    const int n0 = blockIdx.x * 8;

    for (int it = 0; it < 4; ++it){
        int idx = tid + 256*it;
        int node = idx >> 7, o4 = idx & 127;
        float4 v = ((const float4*)(x + (size_t)(n0+node)*512))[o4];
        xl[o4*4+0][node]=v.x; xl[o4*4+1][node]=v.y;
        xl[o4*4+2][node]=v.z; xl[o4*4+3][node]=v.w;
    }
    __syncthreads();

    { // t = [x0, n1]
        int jj = tid;
        if (jj < 128){
            #pragma unroll
            for (int n = 0; n < 8; ++n) tl[jj][n] = xl[jj][n];
        } else {
            int u = jj - 128;
            #pragma unroll
            for (int n = 0; n < 8; ++n){
                float a = xl[128+u*3][n], b = xl[128+u*3+1][n], c = xl[128+u*3+2][n];
                tl[jj][n] = sqrtf((a*a + b*b + c*c) * (1.f/3.f));
            }
        }
    }
    __syncthreads();

    { // h = silu(t @ Wg1 + bg1)
        float acc[8] = {0,0,0,0,0,0,0,0};
        for (int k = 0; k < 256; ++k){
            float w = Wg1[k*256 + tid];
            fma8(acc, &tl[k][0], w);
        }
        float b = bg1[tid];
        #pragma unroll
        for (int n = 0; n < 8; ++n){
            float v = acc[n] + b;
            hl[tid][n] = v / (1.f + expf(-v));
        }
    }
    __syncthreads();

    { // g = h @ Wg2 + bg2  (stored into tl; tl is dead after the barrier)
        float acc[8] = {0,0,0,0,0,0,0,0};
        for (int k = 0; k < 256; ++k){
            float w = Wg2[k*256 + tid];
            fma8(acc, &hl[k][0], w);
        }
        float b = bg2[tid];
        #pragma unroll
        for (int n = 0; n < 8; ++n) tl[tid][n] = acc[n] + b;
    }
    __syncthreads();

    { // xg in-place into xl
        int jj = tid;
        if (jj < 128){
            #pragma unroll
            for (int n = 0; n < 8; ++n) xl[jj][n] = tl[jj][n];
        } else {
            int u = jj - 128;
            #pragma unroll
            for (int n = 0; n < 8; ++n){
                float g1 = tl[128+u][n];
                xl[128+u*3  ][n] *= g1;
                xl[128+u*3+1][n] *= g1;
                xl[128+u*3+2][n] *= g1;
            }
        }
    }
    __syncthreads();

    // nd irrep_linear
    const int j = tid;
    float acc1[8] = {0,0,0,0,0,0,0,0};
    float acc2[8] = {0,0,0,0,0,0,0,0};
    const int o2 = j + 128;
    const int v2 = o2/3, m2 = o2%3;
    if (j < 128){
        for (int u = 0; u < 128; ++u){
            float w1 = Wnd0[u*128 + j];
            float w2 = Wnd1[u*128 + v2];
            fma8(acc1, &xl[u][0], w1);
            fma8(acc2, &xl[128 + u*3 + m2][0], w2);
        }
        float b = bnd0[j];
        #pragma unroll
        for (int n = 0; n < 8; ++n) self_x[(size_t)(n0+n)*512 + j] = acc1[n] + b;
    } else {
        const int o1 = j - 128, v1 = o1/3, m1 = o1%3;
        for (int u = 0; u < 128; ++u){
            float w1 = Wnd1[u*128 + v1];
            float w2 = Wnd1[u*128 + v2];
            fma8(acc1, &xl[128 + u*3 + m1][0], w1);
            fma8(acc2, &xl[128 + u*3 + m2][0], w2);
        }
        #pragma unroll
        for (int n = 0; n < 8; ++n) self_x[(size_t)(n0+n)*512 + j] = acc1[n];
    }
    #pragma unroll
    for (int n = 0; n < 8; ++n) self_x[(size_t)(n0+n)*512 + j + 256] = acc2[n];
}

// ---------------- CSR build: count, scan, fill (arrays hosted in d_out) ----
__global__ __launch_bounds__(256) void k_count(
    const int* __restrict__ eidx, int* __restrict__ cnt)
{
    int e = blockIdx.x * 256 + threadIdx.x;
    if (e < EE){
        int d = eidx[e];
        if (d >= 0 && d < NN) atomicAdd(&cnt[d], 1);
    }
}

__global__ __launch_bounds__(256) void k_scan(
    const int* __restrict__ cnt, int* __restrict__ rowptr, int* __restrict__ cur)
{
    __shared__ int part[256];
    const int t = threadIdx.x;
    const int CHUNK = 79;             // 256*79 = 20224 >= 20000
    const int base = t * CHUNK;
    int s = 0;
    for (int i = 0; i < CHUNK; ++i){
        int idx = base + i;
        if (idx < NN) s += cnt[idx];
    }
    part[t] = s;
    __syncthreads();
    for (int off = 1; off < 256; off <<= 1){
        int v = (t >= off) ? part[t-off] : 0;
        __syncthreads();
        part[t] += v;
        __syncthreads();
    }
    int run = (t == 0) ? 0 : part[t-1];
    for (int i = 0; i < CHUNK; ++i){
        int idx = base + i;
        if (idx < NN){
            rowptr[idx] = run;
            cur[idx]    = run;
            run += cnt[idx];
        }
    }
    if (t == 255) rowptr[NN] = run;
}

__global__ __launch_bounds__(256) void k_fill(
    const int* __restrict__ eidx, int* __restrict__ cur, int2* __restrict__ ebuf,
    int* __restrict__ dstbuf)
{
    int e = blockIdx.x * 256 + threadIdx.x;
    if (e < EE){
        int dst = eidx[e];
        int src = eidx[EE + e];
        if (dst >= 0 && dst < NN){
            int pos = atomicAdd(&cur[dst], 1);
            if (pos >= 0 && pos < EE){
                ebuf[pos] = make_int2(e, src);
                dstbuf[pos] = dst;
            }
        }
    }
}

// ---------------- weight transpose: Wt[q][k] = W[k][q] ---------------------
// Each output channel's 32 k-weights become one contiguous 128B row, so
// k_edge_one's weight-array fill is 8 float4 loads with immediate offsets
// (no per-load 64-bit address arithmetic, full cache-line utilization).
__global__ __launch_bounds__(256) void k_wt(
    const float* __restrict__ Wf2, const float* __restrict__ Ws2,
    float* __restrict__ Wtf, float* __restrict__ Wts)
{
    int idx = blockIdx.x*256 + threadIdx.x;   // 0..16383 = q*32+k
    int q = idx >> 5, k = idx & 31;
    Wtf[idx] = Wf2[(size_t)k*512 + q];
    Wts[idx] = Ws2[(size_t)k*512 + q];
}

// ---------------- K3: edge features in CSR order -> fbuf, sbuf -------------
// Wave-per-edge: lane l computes ip1 for channels 2l,2l+1 from 24B contiguous
// slices of p1[dst]/p1[src] (wave reads each 1536B row fully coalesced, rows
// never staged), writes 2 floats to wave-private LDS. GEMVs split across the
// two half-waves (64/16 iters) + one shfl_xor(32) combine. Tiny register
// footprint by construction; LDS 2KB/block.
__global__ __launch_bounds__(256, 4) void k_edge_pre(
    const float* __restrict__ p1g, const float* __restrict__ sdst,
    const float* __restrict__ ea,
    const int2* __restrict__ ebuf, const int* __restrict__ dstbuf,
    const float* __restrict__ Wf1, const float* __restrict__ Ws1,
    float* __restrict__ fbuf, float* __restrict__ sbuf)
{
    __shared__ float ipw[4][128];
    const int tid  = threadIdx.x;
    const int wv   = tid >> 6, lane = tid & 63;
    const long e   = (long)blockIdx.x * 4 + wv;

    int2 pe = ebuf[e];
    if (!(pe.x >= 0 && pe.x < EE)) pe.x = 0;   // defensive (poison-safe)
    if (!(pe.y >= 0 && pe.y < NN)) pe.y = 0;
    int dst = dstbuf[e];
    if (!(dst >= 0 && dst < NN)) dst = 0;

    // channels u = 2*lane, 2*lane+1  ->  p1 row bytes [24*lane, 24*lane+24)
    const float* pd = p1g + (size_t)dst*384 + lane*6;
    const float* ps = p1g + (size_t)pe.y*384 + lane*6;
    const float2 d01 = *(const float2*)(pd);
    const float2 d23 = *(const float2*)(pd+2);
    const float2 d45 = *(const float2*)(pd+4);
    const float2 s01 = *(const float2*)(ps);
    const float2 s23 = *(const float2*)(ps+2);
    const float2 s45 = *(const float2*)(ps+4);
    const float ipa = (d01.x*s01.x + d01.y*s01.y + d23.x*s23.x) * (1.f/3.f);
    const float ipb = (d23.y*s23.y + d45.x*s45.x + d45.y*s45.y) * (1.f/3.f);
    *(float2*)&ipw[wv][lane*2] = make_float2(ipa, ipb);

    const int h = lane & 31;
    const float sdv = sdst[(size_t)dst*32 + h];   // broadcast per half-wave

    __syncthreads();

    // s-GEMV: half-wave u-split (lane>=32 -> u in [64,128))
    const int uh = (lane >> 5) * 64;
    float sA = 0.f, sB = 0.f;
    #pragma unroll 8
    for (int uu = 0; uu < 64; uu += 2){
        sA += ipw[wv][uh+uu]   * Ws1[(256+uh+uu)*32 + h];
        sB += ipw[wv][uh+uu+1] * Ws1[(257+uh+uu)*32 + h];
    }
    float s = sA + sB;
    s += __shfl_xor(s, 32);

    // f-GEMV: half-wave k-split (16 iters each)
    const int kh = (lane >> 5) * 16;
    const float* ear = ea + (size_t)pe.x*32 + kh;
    float f = 0.f;
    #pragma unroll 8
    for (int kk = 0; kk < 16; ++kk)
        f += ear[kk] * Wf1[(kh+kk)*32 + h];
    f += __shfl_xor(f, 32);

    if (lane < 32){
        sbuf[e*32 + h] = sspf(s + sdv);
        fbuf[e*32 + h] = sspf(f);
    }
}

// ---------------- fused edge GEMM + epilogue + segment reduction -----------
// EXACT R5 structure (best known: 275us, VGPR 84) with ONE register-neutral
// change: the weight arrays are filled from the TRANSPOSED matrices via 8
// contiguous float4 loads (immediate offsets) instead of 32 stride-2KB scalar
// loads — removes per-load 64-bit address arithmetic and makes any compiler
// rematerialization line-efficient. Arrays, LDS staging, sx pipeline, and
// segment logic are bit-identical to R5.
__global__ __launch_bounds__(256) void k_edge_one(
    const float* __restrict__ fbuf, const float* __restrict__ sbuf,
    const float* __restrict__ self_x, const float* __restrict__ esh,
    const int2* __restrict__ ebuf, const int* __restrict__ dstbuf,
    const float* __restrict__ Wtf, const float* __restrict__ Wts,
    float* __restrict__ out)
{
    __shared__ float fbl[64][32];
    __shared__ float sbl[64][32];
    __shared__ float shl[64][4];
    __shared__ float sxl[4][128];      // wave-private sx slice (512B/wave)
    __shared__ int   srcl[64], dl[64];

    const int tid = threadIdx.x;
    const int wv  = tid >> 6;          // wave id
    const int ln  = tid & 63;          // lane
    const int c   = tid >> 1;          // channel 0..127
    const int h   = tid & 1;           // half: 0 -> (w1,w2), 1 -> (w3,w4)
    const long e0 = (long)blockIdx.x * 64;
    const float IS3 = 0.57735026919f;

    // weight arrays (R5 structure) filled from transposed rows: 8 float4
    // loads per array, contiguous, immediate offsets.
    float wfA[32], wfB[32], wsA[32], wsB[32];
    {
        const int qA = 2*h*128 + c, qB = (2*h+1)*128 + c;
        const float4* pfA = (const float4*)(Wtf + (size_t)qA*32);
        const float4* pfB = (const float4*)(Wtf + (size_t)qB*32);
        const float4* psA = (const float4*)(Wts + (size_t)qA*32);
        const float4* psB = (const float4*)(Wts + (size_t)qB*32);
        #pragma unroll
        for (int k4 = 0; k4 < 8; ++k4){
            ((float4*)wfA)[k4] = pfA[k4];
            ((float4*)wfB)[k4] = pfB[k4];
            ((float4*)wsA)[k4] = psA[k4];
            ((float4*)wsB)[k4] = psB[k4];
        }
    }

    if (tid < 64){
        int2 pe = ebuf[e0 + tid];
        if (!(pe.x >= 0 && pe.x < EE)) pe.x = 0;
        if (!(pe.y >= 0 && pe.y < NN)) pe.y = 0;
        int d = dstbuf[e0 + tid];
        if (!(d >= 0 && d < NN)) d = 0;
        srcl[tid] = pe.y; dl[tid] = d;
        ((float4*)shl)[tid] = ((const float4*)esh)[pe.x];
    }
    { // fbuf/sbuf CSR-contiguous: fully coalesced copy, 512 float4 each
        const float4* fsrc = (const float4*)(fbuf + (size_t)e0*32);
        const float4* ssrc = (const float4*)(sbuf + (size_t)e0*32);
        ((float4*)fbl)[tid]       = fsrc[tid];
        ((float4*)fbl)[tid + 256] = fsrc[tid + 256];
        ((float4*)sbl)[tid]       = ssrc[tid];
        ((float4*)sbl)[tid + 256] = ssrc[tid + 256];
    }
    __syncthreads();

    // neighbor dsts for boundary detection (block-uniform)
    const int dprev = (blockIdx.x == 0)    ? -1 : dstbuf[e0 - 1];
    const int dnext = (e0 + 64 < EE)       ? dstbuf[e0 + 64] : -1;

    // sx staging geometry: wave wv needs floats [32wv,32wv+32) (x0 part) and
    // [128+96wv, 128+96wv+96) (v part). lane<16 -> x0 float2, else v float2.
    const int goff = (ln < 16) ? (32*wv + 2*ln) : (128 + 96*wv + 2*(ln-16));
    const int loff = (ln < 16) ? (2*ln)         : (32 + 2*(ln-16));
    const int ci   = c & 31;           // channel index within wave

    // prime pipeline: LDS <- edge0; rA = edge1, rB = edge2 (in flight)
    float2 rA = *(const float2*)(self_x + (size_t)srcl[0]*512 + goff);
    float2 rB = *(const float2*)(self_x + (size_t)srcl[1]*512 + goff);
    float2 rC = *(const float2*)(self_x + (size_t)srcl[2]*512 + goff);
    *(float2*)&sxl[wv][loff] = rA;
    rA = rB; rB = rC;

    float a0 = 0.f, a1 = 0.f;
    int sstart = 0;

    for (int e = 0; e < 64; ++e){
        // issue load for edge e+3 (deepest pipeline stage)
        if (e < 61)
            rC = *(const float2*)(self_x + (size_t)srcl[e+3]*512 + goff);

        // consume edge e from wave-private LDS (2-lane broadcasts, no bank
        // conflicts; wave-synchronous so no barrier needed)
        const float x0c = sxl[wv][ci];
        const float v0  = sxl[wv][32 + 3*ci];
        const float v1  = sxl[wv][32 + 3*ci + 1];
        const float v2  = sxl[wv][32 + 3*ci + 2];

        // dual quadrant dots (all-register FMA; fb/sb are LDS broadcasts)
        float FA = 0.f, FB = 0.f, SA = 0.f, SB = 0.f;
        #pragma unroll
        for (int k4 = 0; k4 < 8; ++k4){
            float4 fb4 = *(const float4*)&fbl[e][k4*4];
            float4 sb4 = *(const float4*)&sbl[e][k4*4];
            FA += fb4.x*wfA[k4*4+0]; FB += fb4.x*wfB[k4*4+0];
            SA += sb4.x*wsA[k4*4+0]; SB += sb4.x*wsB[k4*4+0];
            FA += fb4.y*wfA[k4*4+1]; FB += fb4.y*wfB[k4*4+1];
            SA += sb4.y*wsA[k4*4+1]; SB += sb4.y*wsB[k4*4+1];
            FA += fb4.z*wfA[k4*4+2]; FB += fb4.z*wfB[k4*4+2];
            SA += sb4.z*wsA[k4*4+2]; SB += sb4.z*wsB[k4*4+2];
            FA += fb4.w*wfA[k4*4+3]; FB += fb4.w*wfB[k4*4+3];
            SA += sb4.w*wsA[k4*4+3]; SB += sb4.w*wsB[k4*4+3];
        }
        const float wA = FA*SA, wB = FB*SB;
        const float oA = __shfl_xor(wA, 1);
        const float oB = __shfl_xor(wB, 1);
        // h=0: w1=wA w2=wB w3=oA w4=oB ; h=1: w1=oA w2=oB w3=wA w4=wB
        const float w1 = h ? oA : wA;
        const float w2 = h ? oB : wB;
        const float w3 = h ? wA : oA;
        const float w4 = h ? wB : oB;

        const float4 sh = *(const float4*)&shl[e][0];
        const int dste = dl[e];

        const float dot = v0*sh.y + v1*sh.z + v2*sh.w;
        // h=0: a0 = out0[c],    a1 = out1[c][0]
        // h=1: a0 = out1[c][1], a1 = out1[c][2]
        const float caw = h ? w2 : w1;
        const float cf  = h ? sh.z : sh.x;
        const float cbw = h ? w3 : w4*IS3;
        const float cg  = h ? v1*sh.x : dot;
        a0 += caw*x0c*cf + cbw*cg;
        const float shm = h ? sh.w : sh.y;
        const float vm  = h ? v2 : v0;
        a1 += w2*x0c*shm + w3*vm*sh.x;

        if (e == 63 || dl[e+1] != dste){   // block-uniform segment end
            const bool openL = (sstart == 0) && (dprev == dste);
            const bool openR = (e == 63) && (dnext == dste);
            float* orow = out + (size_t)dste*512;
            const int pos0 = h ? (128 + 3*c + 1) : c;
            const int pos1 = h ? (128 + 3*c + 2) : (128 + 3*c);
            if (openL || openR){
                atomicAdd(orow + pos0, a0);
                atomicAdd(orow + pos1, a1);
            } else {
                orow[pos0] = a0;
                orow[pos1] = a1;
            }
            a0 = 0.f; a1 = 0.f; sstart = e + 1;
        }

        // stage edge e+1 into the wave slice (after edge e was consumed;
        // same-wave DS ops are ordered, no barrier needed)
        if (e < 63){
            *(float2*)&sxl[wv][loff] = rA;
            rA = rB; rB = rC;
        }
    }
}

// ---------------- K5: out linear + residual (in-place over d_out) ----------
__global__ __launch_bounds__(256) void k_post(
    const float* __restrict__ self_x, const float* __restrict__ x,
    const float* __restrict__ Wo0, const float* __restrict__ bo0,
    const float* __restrict__ Wo1,
    float* __restrict__ out)
{
    __shared__ float tl[512][8];
    const int tid = threadIdx.x;
    const int n0 = blockIdx.x * 8;

    for (int it = 0; it < 4; ++it){
        int idx = tid + 256*it;
        int node = idx >> 7, o4 = idx & 127;
        float4 a = ((const float4*)(out    + (size_t)(n0+node)*512))[o4];
        float4 b = ((const float4*)(self_x + (size_t)(n0+node)*512))[o4];
        tl[o4*4+0][node]=a.x+b.x; tl[o4*4+1][node]=a.y+b.y;
        tl[o4*4+2][node]=a.z+b.z; tl[o4*4+3][node]=a.w+b.w;
    }
    __syncthreads();

    const int j = tid;
    float acc1[8] = {0,0,0,0,0,0,0,0};
    float acc2[8] = {0,0,0,0,0,0,0,0};
    const int o2 = j + 128;
    const int v2 = o2/3, m2 = o2%3;
    if (j < 128){
        for (int u = 0; u < 128; ++u){
            float w1 = Wo0[u*128 + j];
            float w2 = Wo1[u*128 + v2];
            fma8(acc1, &tl[u][0], w1);
            fma8(acc2, &tl[128 + u*3 + m2][0], w2);
        }
        float b = bo0[j];
        #pragma unroll
        for (int n = 0; n < 8; ++n)
            out[(size_t)(n0+n)*512 + j] = acc1[n] + b + x[(size_t)(n0+n)*512 + j];
    } else {
        const int o1 = j - 128, v1 = o1/3, m1 = o1%3;
        for (int u = 0; u < 128; ++u){
            float w1 = Wo1[u*128 + v1];
            float w2 = Wo1[u*128 + v2];
            fma8(acc1, &tl[128 + u*3 + m1][0], w1);
            fma8(acc2, &tl[128 + u*3 + m2][0], w2);
        }
        #pragma unroll
        for (int n = 0; n < 8; ++n)
            out[(size_t)(n0+n)*512 + j] = acc1[n] + x[(size_t)(n0+n)*512 + j];
    }
    #pragma unroll
    for (int n = 0; n < 8; ++n)
        out[(size_t)(n0+n)*512 + j + 256] = acc2[n] + x[(size_t)(n0+n)*512 + j + 256];
}

// ---------------------------------------------------------------------------
extern "C" void kernel_launch(void* const* d_in, const int* in_sizes, int n_in,
                              void* d_out, int out_size, void* d_ws, size_t ws_size,
                              hipStream_t stream)
{
    const float* x    = (const float*)d_in[0];
    const float* esh  = (const float*)d_in[1];
    const float* ea   = (const float*)d_in[2];
    const int*   eidx = (const int*)  d_in[3];
    const float* Wp0  = (const float*)d_in[4];
    const float* bp0  = (const float*)d_in[5];
    const float* Wp1  = (const float*)d_in[6];
    const float* Wnd0 = (const float*)d_in[7];
    const float* bnd0 = (const float*)d_in[8];
    const float* Wnd1 = (const float*)d_in[9];
    const float* Wg1  = (const float*)d_in[10];
    const float* bg1  = (const float*)d_in[11];
    const float* Wg2  = (const float*)d_in[12];
    const float* bg2  = (const float*)d_in[13];
    const float* Wf1  = (const float*)d_in[14];
    const float* Wf2  = (const float*)d_in[15];
    const float* Ws1  = (const float*)d_in[16];
    const float* Ws2  = (const float*)d_in[17];
    const float* Wo0  = (const float*)d_in[18];
    const float* bo0  = (const float*)d_in[19];
    const float* Wo1  = (const float*)d_in[20];

    float* out  = (float*)d_out;
    float* ws   = (float*)d_ws;
    float* p1   = ws;                              // N*384 (dead after k_edge_pre)
    float* sdst = p1   + (size_t)NN*384;           // N*32
    float* sfx  = sdst + (size_t)NN*32;            // N*512
    float* fbuf = sfx  + (size_t)NN*512;           // E*32 (CSR-position order)
    float* sbuf = fbuf + (size_t)EE*32;            // E*32

    // CSR build arrays hosted in d_out (2.64 MB of 41 MB; out not needed yet)
    int*  dcnt  = (int*)d_out;                  // NN
    int*  dcur  = dcnt + NN;                    // NN
    int*  drow  = dcur + NN;                    // NN+1 (+3 pad for alignment)
    int2* debuf = (int2*)(drow + NN + 4);       // E int2 (byte 240016, 8-aligned)
    int*  ddst  = (int*)(debuf + EE);           // E int (contiguous after debuf)

    // CSR build first (needs only eidx)
    hipMemsetAsync(dcnt, 0, (size_t)NN*sizeof(int), stream);
    k_count <<<(EE+255)/256, 256, 0, stream>>>(eidx, dcnt);
    k_scan  <<<1, 256, 0, stream>>>(dcnt, drow, dcur);
    k_fill  <<<(EE+255)/256, 256, 0, stream>>>(eidx, dcur, debuf, ddst);

    k_pre     <<<NN/8, 256, 0, stream>>>(x, Wp0, bp0, Wp1, Ws1, p1, sdst);
    k_gate_nd <<<NN/8, 256, 0, stream>>>(x, Wg1, bg1, Wg2, bg2, Wnd0, bnd0, Wnd1, sfx);
    k_edge_pre<<<EE/4, 256, 0, stream>>>(p1, sdst, ea, debuf, ddst, Wf1, Ws1,
                                         fbuf, sbuf);

    // p1 now dead: CSR copy (ebuf+dstbuf, 2.4 MB) into its region, transposed
    // weights (256 KB) just after, then zero out for the scatter.
    int2*  ebuf2   = (int2*)ws;
    int*   dstbuf2 = (int*)ws + (size_t)2*EE;
    float* wtf     = ws + (size_t)3*EE;            // 512*32 floats
    float* wts     = wtf + 512*32;
    k_wt<<<64, 256, 0, stream>>>(Wf2, Ws2, wtf, wts);
    hipMemcpyAsync(ws, debuf, (size_t)3*EE*sizeof(int),
                   hipMemcpyDeviceToDevice, stream);
    hipMemsetAsync(out, 0, (size_t)NN*512*sizeof(float), stream);

    k_edge_one<<<EE/64, 256, 0, stream>>>(fbuf, sbuf, sfx, esh, ebuf2, dstbuf2,
                                          wtf, wts, out);

    k_post    <<<NN/8, 256, 0, stream>>>(sfx, x, Wo0, bo0, Wo1, out);
}

// Round 11
// 923.398 us; speedup vs baseline: 4.0791x; 1.2721x over previous
//
#include <hip/hip_runtime.h>
#include <hip/hip_fp16.h>
#include <math.h>

#define NN 20000
#define EE 200000
// MUL=128, D=512, EDGE_ATTR=32, HID=32

__device__ __forceinline__ float sspf(float x){
    float sp = (x > 20.f) ? x : log1pf(expf(x));
    return sp - 0.69314718056f;
}

__device__ __forceinline__ void fma8(float* acc, const float* base, float w){
    const float4 a = ((const float4*)base)[0];
    const float4 b = ((const float4*)base)[1];
    acc[0]+=a.x*w; acc[1]+=a.y*w; acc[2]+=a.z*w; acc[3]+=a.w*w;
    acc[4]+=b.x*w; acc[5]+=b.y*w; acc[6]+=b.z*w; acc[7]+=b.w*w;
}

// ---------------- K1: pre irrep_linear -> p1, sdst (p0 consumed in-LDS) ----
// x->LDS transpose uses node=flat&7 mapping: store banks (8q + lane&7)%32 ->
// 8-way conflict instead of 64-way (all-lanes-same-bank) of the node=flat>>7
// mapping. Global reads stay line-efficient (8x128B contiguous per wave).
__global__ __launch_bounds__(256) void k_pre(
    const float* __restrict__ x, const float* __restrict__ Wp0,
    const float* __restrict__ bp0, const float* __restrict__ Wp1,
    const float* __restrict__ Ws1,
    float* __restrict__ p1, float* __restrict__ sdst)
{
    __shared__ float xl[512][8];    // transposed [feature][node]
    __shared__ float p0l[8][128];
    const int tid = threadIdx.x;
    const int n0 = blockIdx.x * 8;

    for (int it = 0; it < 4; ++it){
        int flat = tid + 256*it;          // 0..1023 float4 slots
        int node = flat & 7, o4 = flat >> 3;
        float4 v = ((const float4*)(x + (size_t)(n0+node)*512))[o4];
        xl[o4*4+0][node]=v.x; xl[o4*4+1][node]=v.y;
        xl[o4*4+2][node]=v.z; xl[o4*4+3][node]=v.w;
    }
    __syncthreads();

    const int j = tid;
    float acc1[8] = {0,0,0,0,0,0,0,0};
    float acc2[8] = {0,0,0,0,0,0,0,0};
    const int o2 = j + 128;               // p1-index in [128,384)
    const int v2 = o2/3, m2 = o2%3;

    if (j < 128){
        for (int u = 0; u < 128; ++u){
            float w1 = Wp0[u*128 + j];
            float w2 = Wp1[u*128 + v2];
            fma8(acc1, &xl[u][0], w1);
            fma8(acc2, &xl[128 + u*3 + m2][0], w2);
        }
        float b = bp0[j];
        #pragma unroll
        for (int n = 0; n < 8; ++n) p0l[n][j] = acc1[n] + b;
    } else {
        const int o1 = j - 128, v1 = o1/3, m1 = o1%3;
        for (int u = 0; u < 128; ++u){
            float w1 = Wp1[u*128 + v1];
            float w2 = Wp1[u*128 + v2];
            fma8(acc1, &xl[128 + u*3 + m1][0], w1);
            fma8(acc2, &xl[128 + u*3 + m2][0], w2);
        }
        #pragma unroll
        for (int n = 0; n < 8; ++n) p1[(size_t)(n0+n)*384 + (j-128)] = acc1[n];
    }
    #pragma unroll
    for (int n = 0; n < 8; ++n) p1[(size_t)(n0+n)*384 + o2] = acc2[n];
    __syncthreads();

    // sdst = p0 @ (Ws1[0:128] + Ws1[128:256])  (the dst-only part of s0@W_s1)
    {
        int n = tid >> 5, h = tid & 31;
        float s = 0.f;
        for (int u = 0; u < 128; ++u){
            float wc = Ws1[u*32 + h] + Ws1[(128+u)*32 + h];
            s += p0l[n][u] * wc;
        }
        sdst[(size_t)(n0+n)*32 + h] = s;
    }
}

// ---------------- K2: gate + node irrep_linear -> self_x -------------------
__global__ __launch_bounds__(256) void k_gate_nd(
    const float* __restrict__ x,
    const float* __restrict__ Wg1, const float* __restrict__ bg1,
    const float* __restrict__ Wg2, const float* __restrict__ bg2,
    const float* __restrict__ Wnd0, const float* __restrict__ bnd0,
    const float* __restrict__ Wnd1,
    float* __restrict__ self_x)
{
    __shared__ float xl[512][8];
    __shared__ float tl[256][8];   // t, then reused for g
    __shared__ float hl[256][8];
    const int tid = threadIdx.x;
    const int n0 = blockIdx.x * 8;

    for (int it = 0; it < 4; ++it){
        int flat = tid + 256*it;
        int node = flat & 7, o4 = flat >> 3;
        float4 v = ((const float4*)(x + (size_t)(n0+node)*512))[o4];
        xl[o4*4+0][node]=v.x; xl[o4*4+1][node]=v.y;
        xl[o4*4+2][node]=v.z; xl[o4*4+3][node]=v.w;
    }
    __syncthreads();

    { // t = [x0, n1]
        int jj = tid;
        if (jj < 128){
            #pragma unroll
            for (int n = 0; n < 8; ++n) tl[jj][n] = xl[jj][n];
        } else {
            int u = jj - 128;
            #pragma unroll
            for (int n = 0; n < 8; ++n){
                float a = xl[128+u*3][n], b = xl[128+u*3+1][n], c = xl[128+u*3+2][n];
                tl[jj][n] = sqrtf((a*a + b*b + c*c) * (1.f/3.f));
            }
        }
    }
    __syncthreads();

    { // h = silu(t @ Wg1 + bg1)
        float acc[8] = {0,0,0,0,0,0,0,0};
        for (int k = 0; k < 256; ++k){
            float w = Wg1[k*256 + tid];
            fma8(acc, &tl[k][0], w);
        }
        float b = bg1[tid];
        #pragma unroll
        for (int n = 0; n < 8; ++n){
            float v = acc[n] + b;
            hl[tid][n] = v / (1.f + expf(-v));
        }
    }
    __syncthreads();

    { // g = h @ Wg2 + bg2  (stored into tl; tl is dead after the barrier)
        float acc[8] = {0,0,0,0,0,0,0,0};
        for (int k = 0; k < 256; ++k){
            float w = Wg2[k*256 + tid];
            fma8(acc, &hl[k][0], w);
        }
        float b = bg2[tid];
        #pragma unroll
        for (int n = 0; n < 8; ++n) tl[tid][n] = acc[n] + b;
    }
    __syncthreads();

    { // xg in-place into xl
        int jj = tid;
        if (jj < 128){
            #pragma unroll
            for (int n = 0; n < 8; ++n) xl[jj][n] = tl[jj][n];
        } else {
            int u = jj - 128;
            #pragma unroll
            for (int n = 0; n < 8; ++n){
                float g1 = tl[128+u][n];
                xl[128+u*3  ][n] *= g1;
                xl[128+u*3+1][n] *= g1;
                xl[128+u*3+2][n] *= g1;
            }
        }
    }
    __syncthreads();

    // nd irrep_linear
    const int j = tid;
    float acc1[8] = {0,0,0,0,0,0,0,0};
    float acc2[8] = {0,0,0,0,0,0,0,0};
    const int o2 = j + 128;
    const int v2 = o2/3, m2 = o2%3;
    if (j < 128){
        for (int u = 0; u < 128; ++u){
            float w1 = Wnd0[u*128 + j];
            float w2 = Wnd1[u*128 + v2];
            fma8(acc1, &xl[u][0], w1);
            fma8(acc2, &xl[128 + u*3 + m2][0], w2);
        }
        float b = bnd0[j];
        #pragma unroll
        for (int n = 0; n < 8; ++n) self_x[(size_t)(n0+n)*512 + j] = acc1[n] + b;
    } else {
        const int o1 = j - 128, v1 = o1/3, m1 = o1%3;
        for (int u = 0; u < 128; ++u){
            float w1 = Wnd1[u*128 + v1];
            float w2 = Wnd1[u*128 + v2];
            fma8(acc1, &xl[128 + u*3 + m1][0], w1);
            fma8(acc2, &xl[128 + u*3 + m2][0], w2);
        }
        #pragma unroll
        for (int n = 0; n < 8; ++n) self_x[(size_t)(n0+n)*512 + j] = acc1[n];
    }
    #pragma unroll
    for (int n = 0; n < 8; ++n) self_x[(size_t)(n0+n)*512 + j + 256] = acc2[n];
}

// ---------------- CSR build: count, scan, fill (arrays hosted in d_out) ----
__global__ __launch_bounds__(256) void k_count(
    const int* __restrict__ eidx, int* __restrict__ cnt)
{
    int e = blockIdx.x * 256 + threadIdx.x;
    if (e < EE){
        int d = eidx[e];
        if (d >= 0 && d < NN) atomicAdd(&cnt[d], 1);
    }
}

__global__ __launch_bounds__(256) void k_scan(
    const int* __restrict__ cnt, int* __restrict__ rowptr, int* __restrict__ cur)
{
    __shared__ int part[256];
    const int t = threadIdx.x;
    const int CHUNK = 79;             // 256*79 = 20224 >= 20000
    const int base = t * CHUNK;
    int s = 0;
    for (int i = 0; i < CHUNK; ++i){
        int idx = base + i;
        if (idx < NN) s += cnt[idx];
    }
    part[t] = s;
    __syncthreads();
    for (int off = 1; off < 256; off <<= 1){
        int v = (t >= off) ? part[t-off] : 0;
        __syncthreads();
        part[t] += v;
        __syncthreads();
    }
    int run = (t == 0) ? 0 : part[t-1];
    for (int i = 0; i < CHUNK; ++i){
        int idx = base + i;
        if (idx < NN){
            rowptr[idx] = run;
            cur[idx]    = run;
            run += cnt[idx];
        }
    }
    if (t == 255) rowptr[NN] = run;
}

__global__ __launch_bounds__(256) void k_fill(
    const int* __restrict__ eidx, int* __restrict__ cur, int2* __restrict__ ebuf,
    int* __restrict__ dstbuf)
{
    int e = blockIdx.x * 256 + threadIdx.x;
    if (e < EE){
        int dst = eidx[e];
        int src = eidx[EE + e];
        if (dst >= 0 && dst < NN){
            int pos = atomicAdd(&cur[dst], 1);
            if (pos >= 0 && pos < EE){
                ebuf[pos] = make_int2(e, src);
                dstbuf[pos] = dst;
            }
        }
    }
}

// ---------------- K3: edge features in CSR order -> fbuf, sbuf -------------
// Wave-per-edge: lane l computes ip1 for channels 2l,2l+1 from 24B contiguous
// slices of p1[dst]/p1[src] (wave reads each 1536B row fully coalesced, rows
// never staged), writes 2 floats to wave-private LDS. GEMVs split across the
// two half-waves (64/16 iters) + one shfl_xor(32) combine. Tiny register
// footprint by construction; LDS 2KB/block.
__global__ __launch_bounds__(256, 4) void k_edge_pre(
    const float* __restrict__ p1g, const float* __restrict__ sdst,
    const float* __restrict__ ea,
    const int2* __restrict__ ebuf, const int* __restrict__ dstbuf,
    const float* __restrict__ Wf1, const float* __restrict__ Ws1,
    float* __restrict__ fbuf, float* __restrict__ sbuf)
{
    __shared__ float ipw[4][128];
    const int tid  = threadIdx.x;
    const int wv   = tid >> 6, lane = tid & 63;
    const long e   = (long)blockIdx.x * 4 + wv;

    int2 pe = ebuf[e];
    if (!(pe.x >= 0 && pe.x < EE)) pe.x = 0;   // defensive (poison-safe)
    if (!(pe.y >= 0 && pe.y < NN)) pe.y = 0;
    int dst = dstbuf[e];
    if (!(dst >= 0 && dst < NN)) dst = 0;

    // channels u = 2*lane, 2*lane+1  ->  p1 row bytes [24*lane, 24*lane+24)
    const float* pd = p1g + (size_t)dst*384 + lane*6;
    const float* ps = p1g + (size_t)pe.y*384 + lane*6;
    const float2 d01 = *(const float2*)(pd);
    const float2 d23 = *(const float2*)(pd+2);
    const float2 d45 = *(const float2*)(pd+4);
    const float2 s01 = *(const float2*)(ps);
    const float2 s23 = *(const float2*)(ps+2);
    const float2 s45 = *(const float2*)(ps+4);
    const float ipa = (d01.x*s01.x + d01.y*s01.y + d23.x*s23.x) * (1.f/3.f);
    const float ipb = (d23.y*s23.y + d45.x*s45.x + d45.y*s45.y) * (1.f/3.f);
    *(float2*)&ipw[wv][lane*2] = make_float2(ipa, ipb);

    const int h = lane & 31;
    const float sdv = sdst[(size_t)dst*32 + h];   // broadcast per half-wave

    __syncthreads();

    // s-GEMV: half-wave u-split (lane>=32 -> u in [64,128))
    const int uh = (lane >> 5) * 64;
    float sA = 0.f, sB = 0.f;
    #pragma unroll 8
    for (int uu = 0; uu < 64; uu += 2){
        sA += ipw[wv][uh+uu]   * Ws1[(256+uh+uu)*32 + h];
        sB += ipw[wv][uh+uu+1] * Ws1[(257+uh+uu)*32 + h];
    }
    float s = sA + sB;
    s += __shfl_xor(s, 32);

    // f-GEMV: half-wave k-split (16 iters each)
    const int kh = (lane >> 5) * 16;
    const float* ear = ea + (size_t)pe.x*32 + kh;
    float f = 0.f;
    #pragma unroll 8
    for (int kk = 0; kk < 16; ++kk)
        f += ear[kk] * Wf1[(kh+kk)*32 + h];
    f += __shfl_xor(f, 32);

    if (lane < 32){
        sbuf[e*32 + h] = sspf(s + sdv);
        fbuf[e*32 + h] = sspf(f);
    }
}

// ---------------- fused edge GEMM + epilogue + segment reduction -----------
// EXACT R5 configuration (best known: 275us, VGPR 84). Block = 64 CSR edges,
// 256 threads; thread pair = channel c, half h. Weight arrays filled from the
// ORIGINAL k-major Wf2/Ws2 via stride-512 scalar loads — the allocator keeps
// VGPR at 84 (rematerializing from L2), which empirically beats every
// residency-forcing variant (R6-R10: 511-3093us). Do not "fix" this.
__global__ __launch_bounds__(256) void k_edge_one(
    const float* __restrict__ fbuf, const float* __restrict__ sbuf,
    const float* __restrict__ self_x, const float* __restrict__ esh,
    const int2* __restrict__ ebuf, const int* __restrict__ dstbuf,
    const float* __restrict__ Wf2, const float* __restrict__ Ws2,
    float* __restrict__ out)
{
    __shared__ float fbl[64][32];
    __shared__ float sbl[64][32];
    __shared__ float shl[64][4];
    __shared__ float sxl[4][128];      // wave-private sx slice (512B/wave)
    __shared__ int   srcl[64], dl[64];

    const int tid = threadIdx.x;
    const int wv  = tid >> 6;          // wave id
    const int ln  = tid & 63;          // lane
    const int c   = tid >> 1;          // channel 0..127
    const int h   = tid & 1;           // half: 0 -> (w1,w2), 1 -> (w3,w4)
    const long e0 = (long)blockIdx.x * 64;
    const float IS3 = 0.57735026919f;

    // weight columns for quadrants qA=2h, qB=2h+1 (R5 exact)
    float wfA[32], wfB[32], wsA[32], wsB[32];
    {
        const int qA = 2*h*128 + c, qB = (2*h+1)*128 + c;
        #pragma unroll
        for (int k = 0; k < 32; ++k){
            wfA[k] = Wf2[(size_t)k*512 + qA];
            wfB[k] = Wf2[(size_t)k*512 + qB];
            wsA[k] = Ws2[(size_t)k*512 + qA];
            wsB[k] = Ws2[(size_t)k*512 + qB];
        }
    }

    if (tid < 64){
        int2 pe = ebuf[e0 + tid];
        if (!(pe.x >= 0 && pe.x < EE)) pe.x = 0;
        if (!(pe.y >= 0 && pe.y < NN)) pe.y = 0;
        int d = dstbuf[e0 + tid];
        if (!(d >= 0 && d < NN)) d = 0;
        srcl[tid] = pe.y; dl[tid] = d;
        ((float4*)shl)[tid] = ((const float4*)esh)[pe.x];
    }
    { // fbuf/sbuf CSR-contiguous: fully coalesced copy, 512 float4 each
        const float4* fsrc = (const float4*)(fbuf + (size_t)e0*32);
        const float4* ssrc = (const float4*)(sbuf + (size_t)e0*32);
        ((float4*)fbl)[tid]       = fsrc[tid];
        ((float4*)fbl)[tid + 256] = fsrc[tid + 256];
        ((float4*)sbl)[tid]       = ssrc[tid];
        ((float4*)sbl)[tid + 256] = ssrc[tid + 256];
    }
    __syncthreads();

    // neighbor dsts for boundary detection (block-uniform)
    const int dprev = (blockIdx.x == 0)    ? -1 : dstbuf[e0 - 1];
    const int dnext = (e0 + 64 < EE)       ? dstbuf[e0 + 64] : -1;

    // sx staging geometry: wave wv needs floats [32wv,32wv+32) (x0 part) and
    // [128+96wv, 128+96wv+96) (v part). lane<16 -> x0 float2, else v float2.
    const int goff = (ln < 16) ? (32*wv + 2*ln) : (128 + 96*wv + 2*(ln-16));
    const int loff = (ln < 16) ? (2*ln)         : (32 + 2*(ln-16));
    const int ci   = c & 31;           // channel index within wave

    // prime pipeline: LDS <- edge0; rA = edge1, rB = edge2 (in flight)
    float2 rA = *(const float2*)(self_x + (size_t)srcl[0]*512 + goff);
    float2 rB = *(const float2*)(self_x + (size_t)srcl[1]*512 + goff);
    float2 rC = *(const float2*)(self_x + (size_t)srcl[2]*512 + goff);
    *(float2*)&sxl[wv][loff] = rA;
    rA = rB; rB = rC;

    float a0 = 0.f, a1 = 0.f;
    int sstart = 0;

    for (int e = 0; e < 64; ++e){
        // issue load for edge e+3 (deepest pipeline stage)
        if (e < 61)
            rC = *(const float2*)(self_x + (size_t)srcl[e+3]*512 + goff);

        // consume edge e from wave-private LDS (2-lane broadcasts, no bank
        // conflicts; wave-synchronous so no barrier needed)
        const float x0c = sxl[wv][ci];
        const float v0  = sxl[wv][32 + 3*ci];
        const float v1  = sxl[wv][32 + 3*ci + 1];
        const float v2  = sxl[wv][32 + 3*ci + 2];

        // dual quadrant dots (all-register FMA; fb/sb are LDS broadcasts)
        float FA = 0.f, FB = 0.f, SA = 0.f, SB = 0.f;
        #pragma unroll
        for (int k4 = 0; k4 < 8; ++k4){
            float4 fb4 = *(const float4*)&fbl[e][k4*4];
            float4 sb4 = *(const float4*)&sbl[e][k4*4];
            FA += fb4.x*wfA[k4*4+0]; FB += fb4.x*wfB[k4*4+0];
            SA += sb4.x*wsA[k4*4+0]; SB += sb4.x*wsB[k4*4+0];
            FA += fb4.y*wfA[k4*4+1]; FB += fb4.y*wfB[k4*4+1];
            SA += sb4.y*wsA[k4*4+1]; SB += sb4.y*wsB[k4*4+1];
            FA += fb4.z*wfA[k4*4+2]; FB += fb4.z*wfB[k4*4+2];
            SA += sb4.z*wsA[k4*4+2]; SB += sb4.z*wsB[k4*4+2];
            FA += fb4.w*wfA[k4*4+3]; FB += fb4.w*wfB[k4*4+3];
            SA += sb4.w*wsA[k4*4+3]; SB += sb4.w*wsB[k4*4+3];
        }
        const float wA = FA*SA, wB = FB*SB;
        const float oA = __shfl_xor(wA, 1);
        const float oB = __shfl_xor(wB, 1);
        // h=0: w1=wA w2=wB w3=oA w4=oB ; h=1: w1=oA w2=oB w3=wA w4=wB
        const float w1 = h ? oA : wA;
        const float w2 = h ? oB : wB;
        const float w3 = h ? wA : oA;
        const float w4 = h ? wB : oB;

        const float4 sh = *(const float4*)&shl[e][0];
        const int dste = dl[e];

        const float dot = v0*sh.y + v1*sh.z + v2*sh.w;
        // h=0: a0 = out0[c],    a1 = out1[c][0]
        // h=1: a0 = out1[c][1], a1 = out1[c][2]
        const float caw = h ? w2 : w1;
        const float cf  = h ? sh.z : sh.x;
        const float cbw = h ? w3 : w4*IS3;
        const float cg  = h ? v1*sh.x : dot;
        a0 += caw*x0c*cf + cbw*cg;
        const float shm = h ? sh.w : sh.y;
        const float vm  = h ? v2 : v0;
        a1 += w2*x0c*shm + w3*vm*sh.x;

        if (e == 63 || dl[e+1] != dste){   // block-uniform segment end
            const bool openL = (sstart == 0) && (dprev == dste);
            const bool openR = (e == 63) && (dnext == dste);
            float* orow = out + (size_t)dste*512;
            const int pos0 = h ? (128 + 3*c + 1) : c;
            const int pos1 = h ? (128 + 3*c + 2) : (128 + 3*c);
            if (openL || openR){
                atomicAdd(orow + pos0, a0);
                atomicAdd(orow + pos1, a1);
            } else {
                orow[pos0] = a0;
                orow[pos1] = a1;
            }
            a0 = 0.f; a1 = 0.f; sstart = e + 1;
        }

        // stage edge e+1 into the wave slice (after edge e was consumed;
        // same-wave DS ops are ordered, no barrier needed)
        if (e < 63){
            *(float2*)&sxl[wv][loff] = rA;
            rA = rB; rB = rC;
        }
    }
}

// ---------------- K5: out linear + residual (in-place over d_out) ----------
__global__ __launch_bounds__(256) void k_post(
    const float* __restrict__ self_x, const float* __restrict__ x,
    const float* __restrict__ Wo0, const float* __restrict__ bo0,
    const float* __restrict__ Wo1,
    float* __restrict__ out)
{
    __shared__ float tl[512][8];
    const int tid = threadIdx.x;
    const int n0 = blockIdx.x * 8;

    for (int it = 0; it < 4; ++it){
        int flat = tid + 256*it;
        int node = flat & 7, o4 = flat >> 3;
        float4 a = ((const float4*)(out    + (size_t)(n0+node)*512))[o4];
        float4 b = ((const float4*)(self_x + (size_t)(n0+node)*512))[o4];
        tl[o4*4+0][node]=a.x+b.x; tl[o4*4+1][node]=a.y+b.y;
        tl[o4*4+2][node]=a.z+b.z; tl[o4*4+3][node]=a.w+b.w;
    }
    __syncthreads();

    const int j = tid;
    float acc1[8] = {0,0,0,0,0,0,0,0};
    float acc2[8] = {0,0,0,0,0,0,0,0};
    const int o2 = j + 128;
    const int v2 = o2/3, m2 = o2%3;
    if (j < 128){
        for (int u = 0; u < 128; ++u){
            float w1 = Wo0[u*128 + j];
            float w2 = Wo1[u*128 + v2];
            fma8(acc1, &tl[u][0], w1);
            fma8(acc2, &tl[128 + u*3 + m2][0], w2);
        }
        float b = bo0[j];
        #pragma unroll
        for (int n = 0; n < 8; ++n)
            out[(size_t)(n0+n)*512 + j] = acc1[n] + b + x[(size_t)(n0+n)*512 + j];
    } else {
        const int o1 = j - 128, v1 = o1/3, m1 = o1%3;
        for (int u = 0; u < 128; ++u){
            float w1 = Wo1[u*128 + v1];
            float w2 = Wo1[u*128 + v2];
            fma8(acc1, &tl[128 + u*3 + m1][0], w1);
            fma8(acc2, &tl[128 + u*3 + m2][0], w2);
        }
        #pragma unroll
        for (int n = 0; n < 8; ++n)
            out[(size_t)(n0+n)*512 + j] = acc1[n] + x[(size_t)(n0+n)*512 + j];
    }
    #pragma unroll
    for (int n = 0; n < 8; ++n)
        out[(size_t)(n0+n)*512 + j + 256] = acc2[n] + x[(size_t)(n0+n)*512 + j + 256];
}

// ---------------------------------------------------------------------------
extern "C" void kernel_launch(void* const* d_in, const int* in_sizes, int n_in,
                              void* d_out, int out_size, void* d_ws, size_t ws_size,
                              hipStream_t stream)
{
    const float* x    = (const float*)d_in[0];
    const float* esh  = (const float*)d_in[1];
    const float* ea   = (const float*)d_in[2];
    const int*   eidx = (const int*)  d_in[3];
    const float* Wp0  = (const float*)d_in[4];
    const float* bp0  = (const float*)d_in[5];
    const float* Wp1  = (const float*)d_in[6];
    const float* Wnd0 = (const float*)d_in[7];
    const float* bnd0 = (const float*)d_in[8];
    const float* Wnd1 = (const float*)d_in[9];
    const float* Wg1  = (const float*)d_in[10];
    const float* bg1  = (const float*)d_in[11];
    const float* Wg2  = (const float*)d_in[12];
    const float* bg2  = (const float*)d_in[13];
    const float* Wf1  = (const float*)d_in[14];
    const float* Wf2  = (const float*)d_in[15];
    const float* Ws1  = (const float*)d_in[16];
    const float* Ws2  = (const float*)d_in[17];
    const float* Wo0  = (const float*)d_in[18];
    const float* bo0  = (const float*)d_in[19];
    const float* Wo1  = (const float*)d_in[20];

    float* out  = (float*)d_out;
    float* ws   = (float*)d_ws;
    float* p1   = ws;                              // N*384 (dead after k_edge_pre)
    float* sdst = p1   + (size_t)NN*384;           // N*32
    float* sfx  = sdst + (size_t)NN*32;            // N*512
    float* fbuf = sfx  + (size_t)NN*512;           // E*32 (CSR-position order)
    float* sbuf = fbuf + (size_t)EE*32;            // E*32

    // CSR build arrays hosted in d_out (2.64 MB of 41 MB; out not needed yet)
    int*  dcnt  = (int*)d_out;                  // NN
    int*  dcur  = dcnt + NN;                    // NN
    int*  drow  = dcur + NN;                    // NN+1 (+3 pad for alignment)
    int2* debuf = (int2*)(drow + NN + 4);       // E int2 (byte 240016, 8-aligned)
    int*  ddst  = (int*)(debuf + EE);           // E int (contiguous after debuf)

    // CSR build first (needs only eidx)
    hipMemsetAsync(dcnt, 0, (size_t)NN*sizeof(int), stream);
    k_count <<<(EE+255)/256, 256, 0, stream>>>(eidx, dcnt);
    k_scan  <<<1, 256, 0, stream>>>(dcnt, drow, dcur);
    k_fill  <<<(EE+255)/256, 256, 0, stream>>>(eidx, dcur, debuf, ddst);

    k_pre     <<<NN/8, 256, 0, stream>>>(x, Wp0, bp0, Wp1, Ws1, p1, sdst);
    k_gate_nd <<<NN/8, 256, 0, stream>>>(x, Wg1, bg1, Wg2, bg2, Wnd0, bnd0, Wnd1, sfx);
    k_edge_pre<<<EE/4, 256, 0, stream>>>(p1, sdst, ea, debuf, ddst, Wf1, Ws1,
                                         fbuf, sbuf);

    // p1 now dead: move CSR (ebuf+dstbuf, contiguous 2.4 MB) into its region,
    // then zero out for the scatter.
    int2* ebuf2   = (int2*)ws;
    int*  dstbuf2 = (int*)ws + (size_t)2*EE;
    hipMemcpyAsync(ws, debuf, (size_t)3*EE*sizeof(int),
                   hipMemcpyDeviceToDevice, stream);
    hipMemsetAsync(out, 0, (size_t)NN*512*sizeof(float), stream);

    k_edge_one<<<EE/64, 256, 0, stream>>>(fbuf, sbuf, sfx, esh, ebuf2, dstbuf2,
                                          Wf2, Ws2, out);

    k_post    <<<NN/8, 256, 0, stream>>>(sfx, x, Wo0, bo0, Wo1, out);
}

// Round 12
// 919.340 us; speedup vs baseline: 4.0971x; 1.0044x over previous
//
#include <hip/hip_runtime.h>
#include <hip/hip_fp16.h>
#include <math.h>

#define NN 20000
#define EE 200000
// MUL=128, D=512, EDGE_ATTR=32, HID=32

__device__ __forceinline__ float sspf(float x){
    float sp = (x > 20.f) ? x : log1pf(expf(x));
    return sp - 0.69314718056f;
}

__device__ __forceinline__ void fma8(float* acc, const float* base, float w){
    const float4 a = ((const float4*)base)[0];
    const float4 b = ((const float4*)base)[1];
    acc[0]+=a.x*w; acc[1]+=a.y*w; acc[2]+=a.z*w; acc[3]+=a.w*w;
    acc[4]+=b.x*w; acc[5]+=b.y*w; acc[6]+=b.z*w; acc[7]+=b.w*w;
}

// ---------------- K1+K2 fused: pre irrep + gate + node irrep ---------------
// One x read + one LDS transpose feed BOTH the pre-irrep (p1, sdst) and the
// gate+nd path (self_x). Bodies verbatim from the proven split kernels.
// p0l overlays hl's first 4KB (dead before hl's first write; barrier between).
// LDS: xl 16K + tl 8K + hl 8K = 32KB (same as old k_gate_nd -> same occ cap).
__global__ __launch_bounds__(256) void k_node(
    const float* __restrict__ x, const float* __restrict__ Wp0,
    const float* __restrict__ bp0, const float* __restrict__ Wp1,
    const float* __restrict__ Ws1,
    const float* __restrict__ Wg1, const float* __restrict__ bg1,
    const float* __restrict__ Wg2, const float* __restrict__ bg2,
    const float* __restrict__ Wnd0, const float* __restrict__ bnd0,
    const float* __restrict__ Wnd1,
    float* __restrict__ p1, float* __restrict__ sdst,
    float* __restrict__ self_x)
{
    __shared__ float xl[512][8];    // transposed [feature][node]
    __shared__ float tl[256][8];    // t, then reused for g
    __shared__ float hl[256][8];    // h; first 4KB doubles as p0l
    float (*p0l)[128] = (float(*)[128])hl;
    const int tid = threadIdx.x;
    const int n0 = blockIdx.x * 8;

    // transpose (bank-conflict-reduced mapping: node=flat&7)
    for (int it = 0; it < 4; ++it){
        int flat = tid + 256*it;          // 0..1023 float4 slots
        int node = flat & 7, o4 = flat >> 3;
        float4 v = ((const float4*)(x + (size_t)(n0+node)*512))[o4];
        xl[o4*4+0][node]=v.x; xl[o4*4+1][node]=v.y;
        xl[o4*4+2][node]=v.z; xl[o4*4+3][node]=v.w;
    }
    __syncthreads();

    // ---- pre irrep_linear (verbatim k_pre body) ----
    {
        const int j = tid;
        float acc1[8] = {0,0,0,0,0,0,0,0};
        float acc2[8] = {0,0,0,0,0,0,0,0};
        const int o2 = j + 128;               // p1-index in [128,384)
        const int v2 = o2/3, m2 = o2%3;

        if (j < 128){
            for (int u = 0; u < 128; ++u){
                float w1 = Wp0[u*128 + j];
                float w2 = Wp1[u*128 + v2];
                fma8(acc1, &xl[u][0], w1);
                fma8(acc2, &xl[128 + u*3 + m2][0], w2);
            }
            float b = bp0[j];
            #pragma unroll
            for (int n = 0; n < 8; ++n) p0l[n][j] = acc1[n] + b;
        } else {
            const int o1 = j - 128, v1 = o1/3, m1 = o1%3;
            for (int u = 0; u < 128; ++u){
                float w1 = Wp1[u*128 + v1];
                float w2 = Wp1[u*128 + v2];
                fma8(acc1, &xl[128 + u*3 + m1][0], w1);
                fma8(acc2, &xl[128 + u*3 + m2][0], w2);
            }
            #pragma unroll
            for (int n = 0; n < 8; ++n) p1[(size_t)(n0+n)*384 + (j-128)] = acc1[n];
        }
        #pragma unroll
        for (int n = 0; n < 8; ++n) p1[(size_t)(n0+n)*384 + o2] = acc2[n];
    }
    __syncthreads();

    // ---- sdst (reads p0l) and t (reads xl, writes tl) between same barriers
    {
        int n = tid >> 5, h = tid & 31;
        float s = 0.f;
        for (int u = 0; u < 128; ++u){
            float wc = Ws1[u*32 + h] + Ws1[(128+u)*32 + h];
            s += p0l[n][u] * wc;
        }
        sdst[(size_t)(n0+n)*32 + h] = s;
    }
    { // t = [x0, n1]
        int jj = tid;
        if (jj < 128){
            #pragma unroll
            for (int n = 0; n < 8; ++n) tl[jj][n] = xl[jj][n];
        } else {
            int u = jj - 128;
            #pragma unroll
            for (int n = 0; n < 8; ++n){
                float a = xl[128+u*3][n], b = xl[128+u*3+1][n], c = xl[128+u*3+2][n];
                tl[jj][n] = sqrtf((a*a + b*b + c*c) * (1.f/3.f));
            }
        }
    }
    __syncthreads();

    { // h = silu(t @ Wg1 + bg1)   (overwrites p0l region — p0l dead)
        float acc[8] = {0,0,0,0,0,0,0,0};
        for (int k = 0; k < 256; ++k){
            float w = Wg1[k*256 + tid];
            fma8(acc, &tl[k][0], w);
        }
        float b = bg1[tid];
        #pragma unroll
        for (int n = 0; n < 8; ++n){
            float v = acc[n] + b;
            hl[tid][n] = v / (1.f + expf(-v));
        }
    }
    __syncthreads();

    { // g = h @ Wg2 + bg2  (stored into tl; tl is dead after the barrier)
        float acc[8] = {0,0,0,0,0,0,0,0};
        for (int k = 0; k < 256; ++k){
            float w = Wg2[k*256 + tid];
            fma8(acc, &hl[k][0], w);
        }
        float b = bg2[tid];
        #pragma unroll
        for (int n = 0; n < 8; ++n) tl[tid][n] = acc[n] + b;
    }
    __syncthreads();

    { // xg in-place into xl
        int jj = tid;
        if (jj < 128){
            #pragma unroll
            for (int n = 0; n < 8; ++n) xl[jj][n] = tl[jj][n];
        } else {
            int u = jj - 128;
            #pragma unroll
            for (int n = 0; n < 8; ++n){
                float g1 = tl[128+u][n];
                xl[128+u*3  ][n] *= g1;
                xl[128+u*3+1][n] *= g1;
                xl[128+u*3+2][n] *= g1;
            }
        }
    }
    __syncthreads();

    // nd irrep_linear
    {
        const int j = tid;
        float acc1[8] = {0,0,0,0,0,0,0,0};
        float acc2[8] = {0,0,0,0,0,0,0,0};
        const int o2 = j + 128;
        const int v2 = o2/3, m2 = o2%3;
        if (j < 128){
            for (int u = 0; u < 128; ++u){
                float w1 = Wnd0[u*128 + j];
                float w2 = Wnd1[u*128 + v2];
                fma8(acc1, &xl[u][0], w1);
                fma8(acc2, &xl[128 + u*3 + m2][0], w2);
            }
            float b = bnd0[j];
            #pragma unroll
            for (int n = 0; n < 8; ++n) self_x[(size_t)(n0+n)*512 + j] = acc1[n] + b;
        } else {
            const int o1 = j - 128, v1 = o1/3, m1 = o1%3;
            for (int u = 0; u < 128; ++u){
                float w1 = Wnd1[u*128 + v1];
                float w2 = Wnd1[u*128 + v2];
                fma8(acc1, &xl[128 + u*3 + m1][0], w1);
                fma8(acc2, &xl[128 + u*3 + m2][0], w2);
            }
            #pragma unroll
            for (int n = 0; n < 8; ++n) self_x[(size_t)(n0+n)*512 + j] = acc1[n];
        }
        #pragma unroll
        for (int n = 0; n < 8; ++n) self_x[(size_t)(n0+n)*512 + j + 256] = acc2[n];
    }
}

// ---------------- CSR build: count, scan, fill (arrays hosted in d_out) ----
__global__ __launch_bounds__(256) void k_count(
    const int* __restrict__ eidx, int* __restrict__ cnt)
{
    int e = blockIdx.x * 256 + threadIdx.x;
    if (e < EE){
        int d = eidx[e];
        if (d >= 0 && d < NN) atomicAdd(&cnt[d], 1);
    }
}

__global__ __launch_bounds__(256) void k_scan(
    const int* __restrict__ cnt, int* __restrict__ rowptr, int* __restrict__ cur)
{
    __shared__ int part[256];
    const int t = threadIdx.x;
    const int CHUNK = 79;             // 256*79 = 20224 >= 20000
    const int base = t * CHUNK;
    int s = 0;
    for (int i = 0; i < CHUNK; ++i){
        int idx = base + i;
        if (idx < NN) s += cnt[idx];
    }
    part[t] = s;
    __syncthreads();
    for (int off = 1; off < 256; off <<= 1){
        int v = (t >= off) ? part[t-off] : 0;
        __syncthreads();
        part[t] += v;
        __syncthreads();
    }
    int run = (t == 0) ? 0 : part[t-1];
    for (int i = 0; i < CHUNK; ++i){
        int idx = base + i;
        if (idx < NN){
            rowptr[idx] = run;
            cur[idx]    = run;
            run += cnt[idx];
        }
    }
    if (t == 255) rowptr[NN] = run;
}

__global__ __launch_bounds__(256) void k_fill(
    const int* __restrict__ eidx, int* __restrict__ cur, int2* __restrict__ ebuf,
    int* __restrict__ dstbuf)
{
    int e = blockIdx.x * 256 + threadIdx.x;
    if (e < EE){
        int dst = eidx[e];
        int src = eidx[EE + e];
        if (dst >= 0 && dst < NN){
            int pos = atomicAdd(&cur[dst], 1);
            if (pos >= 0 && pos < EE){
                ebuf[pos] = make_int2(e, src);
                dstbuf[pos] = dst;
            }
        }
    }
}

// ---------------- K3: edge features in CSR order -> fbuf, sbuf -------------
// Wave-per-edge: lane l computes ip1 for channels 2l,2l+1 from 24B contiguous
// slices of p1[dst]/p1[src] (wave reads each 1536B row fully coalesced, rows
// never staged), writes 2 floats to wave-private LDS. GEMVs split across the
// two half-waves (64/16 iters) + one shfl_xor(32) combine. Tiny register
// footprint by construction; LDS 2KB/block.
__global__ __launch_bounds__(256, 4) void k_edge_pre(
    const float* __restrict__ p1g, const float* __restrict__ sdst,
    const float* __restrict__ ea,
    const int2* __restrict__ ebuf, const int* __restrict__ dstbuf,
    const float* __restrict__ Wf1, const float* __restrict__ Ws1,
    float* __restrict__ fbuf, float* __restrict__ sbuf)
{
    __shared__ float ipw[4][128];
    const int tid  = threadIdx.x;
    const int wv   = tid >> 6, lane = tid & 63;
    const long e   = (long)blockIdx.x * 4 + wv;

    int2 pe = ebuf[e];
    if (!(pe.x >= 0 && pe.x < EE)) pe.x = 0;   // defensive (poison-safe)
    if (!(pe.y >= 0 && pe.y < NN)) pe.y = 0;
    int dst = dstbuf[e];
    if (!(dst >= 0 && dst < NN)) dst = 0;

    // channels u = 2*lane, 2*lane+1  ->  p1 row bytes [24*lane, 24*lane+24)
    const float* pd = p1g + (size_t)dst*384 + lane*6;
    const float* ps = p1g + (size_t)pe.y*384 + lane*6;
    const float2 d01 = *(const float2*)(pd);
    const float2 d23 = *(const float2*)(pd+2);
    const float2 d45 = *(const float2*)(pd+4);
    const float2 s01 = *(const float2*)(ps);
    const float2 s23 = *(const float2*)(ps+2);
    const float2 s45 = *(const float2*)(ps+4);
    const float ipa = (d01.x*s01.x + d01.y*s01.y + d23.x*s23.x) * (1.f/3.f);
    const float ipb = (d23.y*s23.y + d45.x*s45.x + d45.y*s45.y) * (1.f/3.f);
    *(float2*)&ipw[wv][lane*2] = make_float2(ipa, ipb);

    const int h = lane & 31;
    const float sdv = sdst[(size_t)dst*32 + h];   // broadcast per half-wave

    __syncthreads();

    // s-GEMV: half-wave u-split (lane>=32 -> u in [64,128))
    const int uh = (lane >> 5) * 64;
    float sA = 0.f, sB = 0.f;
    #pragma unroll 8
    for (int uu = 0; uu < 64; uu += 2){
        sA += ipw[wv][uh+uu]   * Ws1[(256+uh+uu)*32 + h];
        sB += ipw[wv][uh+uu+1] * Ws1[(257+uh+uu)*32 + h];
    }
    float s = sA + sB;
    s += __shfl_xor(s, 32);

    // f-GEMV: half-wave k-split (16 iters each)
    const int kh = (lane >> 5) * 16;
    const float* ear = ea + (size_t)pe.x*32 + kh;
    float f = 0.f;
    #pragma unroll 8
    for (int kk = 0; kk < 16; ++kk)
        f += ear[kk] * Wf1[(kh+kk)*32 + h];
    f += __shfl_xor(f, 32);

    if (lane < 32){
        sbuf[e*32 + h] = sspf(s + sdv);
        fbuf[e*32 + h] = sspf(f);
    }
}

// ---------------- fused edge GEMM + epilogue + segment reduction -----------
// EXACT R5 configuration (best known: 277us, VGPR 84). Block = 64 CSR edges,
// 256 threads; thread pair = channel c, half h. Weight arrays filled from the
// ORIGINAL k-major Wf2/Ws2 via stride-512 scalar loads — the allocator keeps
// VGPR at 84 (rematerializing from L2), which empirically beats every
// residency-forcing variant (R6-R10: 511-3093us). Do not "fix" this.
__global__ __launch_bounds__(256) void k_edge_one(
    const float* __restrict__ fbuf, const float* __restrict__ sbuf,
    const float* __restrict__ self_x, const float* __restrict__ esh,
    const int2* __restrict__ ebuf, const int* __restrict__ dstbuf,
    const float* __restrict__ Wf2, const float* __restrict__ Ws2,
    float* __restrict__ out)
{
    __shared__ float fbl[64][32];
    __shared__ float sbl[64][32];
    __shared__ float shl[64][4];
    __shared__ float sxl[4][128];      // wave-private sx slice (512B/wave)
    __shared__ int   srcl[64], dl[64];

    const int tid = threadIdx.x;
    const int wv  = tid >> 6;          // wave id
    const int ln  = tid & 63;          // lane
    const int c   = tid >> 1;          // channel 0..127
    const int h   = tid & 1;           // half: 0 -> (w1,w2), 1 -> (w3,w4)
    const long e0 = (long)blockIdx.x * 64;
    const float IS3 = 0.57735026919f;

    // weight columns for quadrants qA=2h, qB=2h+1 (R5 exact)
    float wfA[32], wfB[32], wsA[32], wsB[32];
    {
        const int qA = 2*h*128 + c, qB = (2*h+1)*128 + c;
        #pragma unroll
        for (int k = 0; k < 32; ++k){
            wfA[k] = Wf2[(size_t)k*512 + qA];
            wfB[k] = Wf2[(size_t)k*512 + qB];
            wsA[k] = Ws2[(size_t)k*512 + qA];
            wsB[k] = Ws2[(size_t)k*512 + qB];
        }
    }

    if (tid < 64){
        int2 pe = ebuf[e0 + tid];
        if (!(pe.x >= 0 && pe.x < EE)) pe.x = 0;
        if (!(pe.y >= 0 && pe.y < NN)) pe.y = 0;
        int d = dstbuf[e0 + tid];
        if (!(d >= 0 && d < NN)) d = 0;
        srcl[tid] = pe.y; dl[tid] = d;
        ((float4*)shl)[tid] = ((const float4*)esh)[pe.x];
    }
    { // fbuf/sbuf CSR-contiguous: fully coalesced copy, 512 float4 each
        const float4* fsrc = (const float4*)(fbuf + (size_t)e0*32);
        const float4* ssrc = (const float4*)(sbuf + (size_t)e0*32);
        ((float4*)fbl)[tid]       = fsrc[tid];
        ((float4*)fbl)[tid + 256] = fsrc[tid + 256];
        ((float4*)sbl)[tid]       = ssrc[tid];
        ((float4*)sbl)[tid + 256] = ssrc[tid + 256];
    }
    __syncthreads();

    // neighbor dsts for boundary detection (block-uniform)
    const int dprev = (blockIdx.x == 0)    ? -1 : dstbuf[e0 - 1];
    const int dnext = (e0 + 64 < EE)       ? dstbuf[e0 + 64] : -1;

    // sx staging geometry: wave wv needs floats [32wv,32wv+32) (x0 part) and
    // [128+96wv, 128+96wv+96) (v part). lane<16 -> x0 float2, else v float2.
    const int goff = (ln < 16) ? (32*wv + 2*ln) : (128 + 96*wv + 2*(ln-16));
    const int loff = (ln < 16) ? (2*ln)         : (32 + 2*(ln-16));
    const int ci   = c & 31;           // channel index within wave

    // prime pipeline: LDS <- edge0; rA = edge1, rB = edge2 (in flight)
    float2 rA = *(const float2*)(self_x + (size_t)srcl[0]*512 + goff);
    float2 rB = *(const float2*)(self_x + (size_t)srcl[1]*512 + goff);
    float2 rC = *(const float2*)(self_x + (size_t)srcl[2]*512 + goff);
    *(float2*)&sxl[wv][loff] = rA;
    rA = rB; rB = rC;

    float a0 = 0.f, a1 = 0.f;
    int sstart = 0;

    for (int e = 0; e < 64; ++e){
        // issue load for edge e+3 (deepest pipeline stage)
        if (e < 61)
            rC = *(const float2*)(self_x + (size_t)srcl[e+3]*512 + goff);

        // consume edge e from wave-private LDS (2-lane broadcasts, no bank
        // conflicts; wave-synchronous so no barrier needed)
        const float x0c = sxl[wv][ci];
        const float v0  = sxl[wv][32 + 3*ci];
        const float v1  = sxl[wv][32 + 3*ci + 1];
        const float v2  = sxl[wv][32 + 3*ci + 2];

        // dual quadrant dots (all-register FMA; fb/sb are LDS broadcasts)
        float FA = 0.f, FB = 0.f, SA = 0.f, SB = 0.f;
        #pragma unroll
        for (int k4 = 0; k4 < 8; ++k4){
            float4 fb4 = *(const float4*)&fbl[e][k4*4];
            float4 sb4 = *(const float4*)&sbl[e][k4*4];
            FA += fb4.x*wfA[k4*4+0]; FB += fb4.x*wfB[k4*4+0];
            SA += sb4.x*wsA[k4*4+0]; SB += sb4.x*wsB[k4*4+0];
            FA += fb4.y*wfA[k4*4+1]; FB += fb4.y*wfB[k4*4+1];
            SA += sb4.y*wsA[k4*4+1]; SB += sb4.y*wsB[k4*4+1];
            FA += fb4.z*wfA[k4*4+2]; FB += fb4.z*wfB[k4*4+2];
            SA += sb4.z*wsA[k4*4+2]; SB += sb4.z*wsB[k4*4+2];
            FA += fb4.w*wfA[k4*4+3]; FB += fb4.w*wfB[k4*4+3];
            SA += sb4.w*wsA[k4*4+3]; SB += sb4.w*wsB[k4*4+3];
        }
        const float wA = FA*SA, wB = FB*SB;
        const float oA = __shfl_xor(wA, 1);
        const float oB = __shfl_xor(wB, 1);
        // h=0: w1=wA w2=wB w3=oA w4=oB ; h=1: w1=oA w2=oB w3=wA w4=wB
        const float w1 = h ? oA : wA;
        const float w2 = h ? oB : wB;
        const float w3 = h ? wA : oA;
        const float w4 = h ? wB : oB;

        const float4 sh = *(const float4*)&shl[e][0];
        const int dste = dl[e];

        const float dot = v0*sh.y + v1*sh.z + v2*sh.w;
        // h=0: a0 = out0[c],    a1 = out1[c][0]
        // h=1: a0 = out1[c][1], a1 = out1[c][2]
        const float caw = h ? w2 : w1;
        const float cf  = h ? sh.z : sh.x;
        const float cbw = h ? w3 : w4*IS3;
        const float cg  = h ? v1*sh.x : dot;
        a0 += caw*x0c*cf + cbw*cg;
        const float shm = h ? sh.w : sh.y;
        const float vm  = h ? v2 : v0;
        a1 += w2*x0c*shm + w3*vm*sh.x;

        if (e == 63 || dl[e+1] != dste){   // block-uniform segment end
            const bool openL = (sstart == 0) && (dprev == dste);
            const bool openR = (e == 63) && (dnext == dste);
            float* orow = out + (size_t)dste*512;
            const int pos0 = h ? (128 + 3*c + 1) : c;
            const int pos1 = h ? (128 + 3*c + 2) : (128 + 3*c);
            if (openL || openR){
                atomicAdd(orow + pos0, a0);
                atomicAdd(orow + pos1, a1);
            } else {
                orow[pos0] = a0;
                orow[pos1] = a1;
            }
            a0 = 0.f; a1 = 0.f; sstart = e + 1;
        }

        // stage edge e+1 into the wave slice (after edge e was consumed;
        // same-wave DS ops are ordered, no barrier needed)
        if (e < 63){
            *(float2*)&sxl[wv][loff] = rA;
            rA = rB; rB = rC;
        }
    }
}

// ---------------- K5: out linear + residual (in-place over d_out) ----------
__global__ __launch_bounds__(256) void k_post(
    const float* __restrict__ self_x, const float* __restrict__ x,
    const float* __restrict__ Wo0, const float* __restrict__ bo0,
    const float* __restrict__ Wo1,
    float* __restrict__ out)
{
    __shared__ float tl[512][8];
    const int tid = threadIdx.x;
    const int n0 = blockIdx.x * 8;

    for (int it = 0; it < 4; ++it){
        int flat = tid + 256*it;
        int node = flat & 7, o4 = flat >> 3;
        float4 a = ((const float4*)(out    + (size_t)(n0+node)*512))[o4];
        float4 b = ((const float4*)(self_x + (size_t)(n0+node)*512))[o4];
        tl[o4*4+0][node]=a.x+b.x; tl[o4*4+1][node]=a.y+b.y;
        tl[o4*4+2][node]=a.z+b.z; tl[o4*4+3][node]=a.w+b.w;
    }
    __syncthreads();

    const int j = tid;
    float acc1[8] = {0,0,0,0,0,0,0,0};
    float acc2[8] = {0,0,0,0,0,0,0,0};
    const int o2 = j + 128;
    const int v2 = o2/3, m2 = o2%3;
    if (j < 128){
        for (int u = 0; u < 128; ++u){
            float w1 = Wo0[u*128 + j];
            float w2 = Wo1[u*128 + v2];
            fma8(acc1, &tl[u][0], w1);
            fma8(acc2, &tl[128 + u*3 + m2][0], w2);
        }
        float b = bo0[j];
        #pragma unroll
        for (int n = 0; n < 8; ++n)
            out[(size_t)(n0+n)*512 + j] = acc1[n] + b + x[(size_t)(n0+n)*512 + j];
    } else {
        const int o1 = j - 128, v1 = o1/3, m1 = o1%3;
        for (int u = 0; u < 128; ++u){
            float w1 = Wo1[u*128 + v1];
            float w2 = Wo1[u*128 + v2];
            fma8(acc1, &tl[128 + u*3 + m1][0], w1);
            fma8(acc2, &tl[128 + u*3 + m2][0], w2);
        }
        #pragma unroll
        for (int n = 0; n < 8; ++n)
            out[(size_t)(n0+n)*512 + j] = acc1[n] + x[(size_t)(n0+n)*512 + j];
    }
    #pragma unroll
    for (int n = 0; n < 8; ++n)
        out[(size_t)(n0+n)*512 + j + 256] = acc2[n] + x[(size_t)(n0+n)*512 + j + 256];
}

// ---------------------------------------------------------------------------
extern "C" void kernel_launch(void* const* d_in, const int* in_sizes, int n_in,
                              void* d_out, int out_size, void* d_ws, size_t ws_size,
                              hipStream_t stream)
{
    const float* x    = (const float*)d_in[0];
    const float* esh  = (const float*)d_in[1];
    const float* ea   = (const float*)d_in[2];
    const int*   eidx = (const int*)  d_in[3];
    const float* Wp0  = (const float*)d_in[4];
    const float* bp0  = (const float*)d_in[5];
    const float* Wp1  = (const float*)d_in[6];
    const float* Wnd0 = (const float*)d_in[7];
    const float* bnd0 = (const float*)d_in[8];
    const float* Wnd1 = (const float*)d_in[9];
    const float* Wg1  = (const float*)d_in[10];
    const float* bg1  = (const float*)d_in[11];
    const float* Wg2  = (const float*)d_in[12];
    const float* bg2  = (const float*)d_in[13];
    const float* Wf1  = (const float*)d_in[14];
    const float* Wf2  = (const float*)d_in[15];
    const float* Ws1  = (const float*)d_in[16];
    const float* Ws2  = (const float*)d_in[17];
    const float* Wo0  = (const float*)d_in[18];
    const float* bo0  = (const float*)d_in[19];
    const float* Wo1  = (const float*)d_in[20];

    float* out  = (float*)d_out;
    float* ws   = (float*)d_ws;
    float* p1   = ws;                              // N*384 (dead after k_edge_pre)
    float* sdst = p1   + (size_t)NN*384;           // N*32
    float* sfx  = sdst + (size_t)NN*32;            // N*512
    float* fbuf = sfx  + (size_t)NN*512;           // E*32 (CSR-position order)
    float* sbuf = fbuf + (size_t)EE*32;            // E*32

    // CSR build arrays hosted in d_out (2.64 MB of 41 MB; out not needed yet)
    int*  dcnt  = (int*)d_out;                  // NN
    int*  dcur  = dcnt + NN;                    // NN
    int*  drow  = dcur + NN;                    // NN+1 (+3 pad for alignment)
    int2* debuf = (int2*)(drow + NN + 4);       // E int2 (byte 240016, 8-aligned)
    int*  ddst  = (int*)(debuf + EE);           // E int (contiguous after debuf)

    // CSR build first (needs only eidx)
    hipMemsetAsync(dcnt, 0, (size_t)NN*sizeof(int), stream);
    k_count <<<(EE+255)/256, 256, 0, stream>>>(eidx, dcnt);
    k_scan  <<<1, 256, 0, stream>>>(dcnt, drow, dcur);
    k_fill  <<<(EE+255)/256, 256, 0, stream>>>(eidx, dcur, debuf, ddst);

    k_node    <<<NN/8, 256, 0, stream>>>(x, Wp0, bp0, Wp1, Ws1,
                                         Wg1, bg1, Wg2, bg2, Wnd0, bnd0, Wnd1,
                                         p1, sdst, sfx);
    k_edge_pre<<<EE/4, 256, 0, stream>>>(p1, sdst, ea, debuf, ddst, Wf1, Ws1,
                                         fbuf, sbuf);

    // p1 now dead: move CSR (ebuf+dstbuf, contiguous 2.4 MB) into its region,
    // then zero out for the scatter.
    int2* ebuf2   = (int2*)ws;
    int*  dstbuf2 = (int*)ws + (size_t)2*EE;
    hipMemcpyAsync(ws, debuf, (size_t)3*EE*sizeof(int),
                   hipMemcpyDeviceToDevice, stream);
    hipMemsetAsync(out, 0, (size_t)NN*512*sizeof(float), stream);

    k_edge_one<<<EE/64, 256, 0, stream>>>(fbuf, sbuf, sfx, esh, ebuf2, dstbuf2,
                                          Wf2, Ws2, out);

    k_post    <<<NN/8, 256, 0, stream>>>(sfx, x, Wo0, bo0, Wo1, out);
}